// Round 1
// baseline (236.311 us; speedup 1.0000x reference)
//
#include <hip/hip_runtime.h>
#include <stdint.h>

// GaussianKernelSimilarity: z[8192,1024] f32, expert_keys[4096,1024] f32
// out0 = exp(-max(|z|^2+|e|^2-2 z.e, 0)/2)  [8192,4096]
// out1 = softmax(out0, axis=-1) @ expert_keys [8192,1024]
// Strategy: bf16 MFMA for both GEMMs (137 GFLOP total), fused exp+rowsum
// epilogue in GEMM1, softmax denominator as sum(exp(sim)) (== max-subtracted
// form mathematically), elementwise weights pass, gemm_bt template reused.

#define M_TOK 8192
#define N_EXP 4096
#define D_DIM 1024

typedef __attribute__((ext_vector_type(4))) float f32x4;
typedef __attribute__((ext_vector_type(8))) short short8;
typedef unsigned short u16;
typedef unsigned int u32;

__device__ __forceinline__ u16 f32_to_bf16(float f) {
  u32 u = __builtin_bit_cast(u32, f);
  u += 0x7fff + ((u >> 16) & 1);   // round-to-nearest-even
  return (u16)(u >> 16);
}

__device__ __forceinline__ void async16(const void* g, void* l) {
  __builtin_amdgcn_global_load_lds((__attribute__((address_space(1))) void*)(g),
                                   (__attribute__((address_space(3))) void*)(l),
                                   16, 0, 0);
}

// ---- prep: f32 -> bf16 row convert + row sum of squares -------------------
__global__ __launch_bounds__(256) void prep_convert(const float* __restrict__ src,
                                                    u16* __restrict__ dst,
                                                    float* __restrict__ sq) {
  int row = blockIdx.x;
  int t = threadIdx.x;                       // 256 threads, 4 elems each (D=1024)
  const float4 v = ((const float4*)(src + (size_t)row * D_DIM))[t];
  ushort4 h;
  h.x = f32_to_bf16(v.x); h.y = f32_to_bf16(v.y);
  h.z = f32_to_bf16(v.z); h.w = f32_to_bf16(v.w);
  ((ushort4*)(dst + (size_t)row * D_DIM))[t] = h;
  float p = v.x * v.x + v.y * v.y + v.z * v.z + v.w * v.w;
#pragma unroll
  for (int off = 1; off < 64; off <<= 1) p += __shfl_xor(p, off, 64);
  __shared__ float partial[4];
  if ((t & 63) == 0) partial[t >> 6] = p;
  __syncthreads();
  if (t == 0) sq[row] = partial[0] + partial[1] + partial[2] + partial[3];
}

// ---- bf16 transpose: eb[4096][1024] -> ebT[1024][4096] --------------------
__global__ __launch_bounds__(256) void transpose_bf16(const u16* __restrict__ src,
                                                      u16* __restrict__ dst) {
  __shared__ u16 tile[64][65];
  int e0 = blockIdx.x * 64;   // src row block (expert idx)
  int d0 = blockIdx.y * 64;   // src col block (dim idx)
  int t = threadIdx.x;
  int lr = t >> 4;            // 0..15
  int lc = (t & 15) * 4;      // 0..60
#pragma unroll
  for (int r8 = 0; r8 < 4; ++r8) {
    int row = lr + r8 * 16;
    ushort4 v = *(const ushort4*)(src + (size_t)(e0 + row) * D_DIM + d0 + lc);
    tile[row][lc + 0] = v.x; tile[row][lc + 1] = v.y;
    tile[row][lc + 2] = v.z; tile[row][lc + 3] = v.w;
  }
  __syncthreads();
#pragma unroll
  for (int r8 = 0; r8 < 4; ++r8) {
    int dl = lr + r8 * 16;
    ushort4 v;
    v.x = tile[lc + 0][dl]; v.y = tile[lc + 1][dl];
    v.z = tile[lc + 2][dl]; v.w = tile[lc + 3][dl];
    *(ushort4*)(dst + (size_t)(d0 + dl) * N_EXP + e0 + lc) = v;
  }
}

// ---- gemm_bt: C[M,N] = A[M,K] * Bt[N,K]^T, bf16 MFMA 16x16x32 -------------
// 128x128 tile, BK=64, 4 waves (2x2), 64x64 per wave, 4x4 fragments.
// LDS XOR-swizzle (byte ^= (row&7)<<4) applied on the READ side; staging via
// global_load_lds writes linearly, so the global SOURCE address is
// pre-swizzled with the same involution (guide §5/m201/m173 pattern).
// EPI=1: similarity epilogue (dist2 -> exp -> store + rowsum atomics)
// EPI=0: plain store.
template <int EPI>
__global__ __launch_bounds__(256) void gemm_bt(const u16* __restrict__ A,
                                               const u16* __restrict__ Bt,
                                               int Mdim, int Ndim, int Kdim,
                                               float* __restrict__ out, int ldo,
                                               const float* __restrict__ a_sq,
                                               const float* __restrict__ b_sq,
                                               float* __restrict__ rowsum) {
  constexpr int BM = 128, BN = 128, BK = 64;
  __shared__ __align__(16) u16 smA[BM * BK];
  __shared__ __align__(16) u16 smB[BN * BK];

  const int nTilesN = Ndim / BN;
  const int nwg = (Mdim / BM) * nTilesN;
  const int cpx = nwg >> 3;                    // nwg % 8 == 0 for both gemms
  const int wg = blockIdx.x;
  const int swz = (wg & 7) * cpx + (wg >> 3);  // XCD-aware swizzle
  const int m0 = (swz / nTilesN) * BM;
  const int n0 = (swz % nTilesN) * BN;

  const int t = threadIdx.x;
  const int l = t & 63;
  const int w = t >> 6;          // wave 0..3
  const int wr = w >> 1, wc = w & 1;

  // staging: issue s covers LDS rows [s*8, s*8+8); lane l -> row s*8 + l/8,
  // source col pre-swizzled: 8*((l%8) ^ (l/8)) elements.
  const int lr8 = l >> 3;
  const int cswz = (((l & 7) ^ lr8) << 3);

  f32x4 acc[4][4];
#pragma unroll
  for (int i = 0; i < 4; ++i)
#pragma unroll
    for (int j = 0; j < 4; ++j) acc[i][j] = (f32x4){0.f, 0.f, 0.f, 0.f};

  for (int k0 = 0; k0 < Kdim; k0 += BK) {
    __syncthreads();
#pragma unroll
    for (int i = 0; i < 4; ++i) {
      int s = i * 4 + w;
      int row = s * 8 + lr8;
      async16(A + (size_t)(m0 + row) * Kdim + k0 + cswz, smA + s * 512);
    }
#pragma unroll
    for (int i = 0; i < 4; ++i) {
      int s = i * 4 + w;
      int row = s * 8 + lr8;
      async16(Bt + (size_t)(n0 + row) * Kdim + k0 + cswz, smB + s * 512);
    }
    __syncthreads();   // compiler drains vmcnt(0) before barrier

#pragma unroll
    for (int ks = 0; ks < 2; ++ks) {
      short8 af[4], bf[4];
      const int lrow = l & 15;
      const int kb = ks * 64 + ((l >> 4) << 4);   // byte offset in row
#pragma unroll
      for (int mi = 0; mi < 4; ++mi) {
        int row = wr * 64 + mi * 16 + lrow;
        int addr = row * 128 + (kb ^ ((row & 7) << 4));
        af[mi] = *(const short8*)(smA + (addr >> 1));
      }
#pragma unroll
      for (int ni = 0; ni < 4; ++ni) {
        int row = wc * 64 + ni * 16 + lrow;
        int addr = row * 128 + (kb ^ ((row & 7) << 4));
        bf[ni] = *(const short8*)(smB + (addr >> 1));
      }
#pragma unroll
      for (int mi = 0; mi < 4; ++mi)
#pragma unroll
        for (int ni = 0; ni < 4; ++ni)
          acc[mi][ni] = __builtin_amdgcn_mfma_f32_16x16x32_bf16(
              af[mi], bf[ni], acc[mi][ni], 0, 0, 0);
    }
  }

  // epilogue: C/D layout col = lane&15, row = (lane>>4)*4 + reg  [m89]
  const int lrow16 = l & 15;
  const int rgrp = l >> 4;
  if (EPI == 1) {
    float eq[4];
#pragma unroll
    for (int ni = 0; ni < 4; ++ni)
      eq[ni] = b_sq[n0 + wc * 64 + ni * 16 + lrow16];
#pragma unroll
    for (int mi = 0; mi < 4; ++mi) {
#pragma unroll
      for (int r = 0; r < 4; ++r) {
        int grow = m0 + wr * 64 + mi * 16 + rgrp * 4 + r;
        float zq = a_sq[grow];
        float esum = 0.f;
#pragma unroll
        for (int ni = 0; ni < 4; ++ni) {
          int gcol = n0 + wc * 64 + ni * 16 + lrow16;
          float dist2 = zq + eq[ni] - 2.0f * acc[mi][ni][r];
          dist2 = fmaxf(dist2, 0.0f);
          float sim = __expf(-0.5f * dist2);
          out[(size_t)grow * ldo + gcol] = sim;
          esum += __expf(sim);   // softmax denominator (no max-sub needed: sim in [0,1])
        }
#pragma unroll
        for (int off = 1; off < 16; off <<= 1) esum += __shfl_xor(esum, off, 64);
        if (lrow16 == 0) atomicAdd(&rowsum[grow], esum);
      }
    }
  } else {
#pragma unroll
    for (int mi = 0; mi < 4; ++mi)
#pragma unroll
      for (int r = 0; r < 4; ++r) {
        int grow = m0 + wr * 64 + mi * 16 + rgrp * 4 + r;
#pragma unroll
        for (int ni = 0; ni < 4; ++ni) {
          int gcol = n0 + wc * 64 + ni * 16 + lrow16;
          out[(size_t)grow * ldo + gcol] = acc[mi][ni][r];
        }
      }
  }
}

// ---- weights: w = exp(sim)/rowsum, store bf16 -----------------------------
__global__ __launch_bounds__(256) void weights_kernel(const float* __restrict__ sim,
                                                      const float* __restrict__ rowsum,
                                                      u16* __restrict__ wb) {
  size_t i = ((size_t)blockIdx.x * 256 + threadIdx.x) * 8;
  int row = (int)(i >> 12);                  // / 4096
  float inv = 1.0f / rowsum[row];
  float4 a = *(const float4*)(sim + i);
  float4 b = *(const float4*)(sim + i + 4);
  u32 w0 = (u32)f32_to_bf16(__expf(a.x) * inv) | ((u32)f32_to_bf16(__expf(a.y) * inv) << 16);
  u32 w1 = (u32)f32_to_bf16(__expf(a.z) * inv) | ((u32)f32_to_bf16(__expf(a.w) * inv) << 16);
  u32 w2 = (u32)f32_to_bf16(__expf(b.x) * inv) | ((u32)f32_to_bf16(__expf(b.y) * inv) << 16);
  u32 w3 = (u32)f32_to_bf16(__expf(b.z) * inv) | ((u32)f32_to_bf16(__expf(b.w) * inv) << 16);
  uint4 o; o.x = w0; o.y = w1; o.z = w2; o.w = w3;
  *(uint4*)(wb + i) = o;
}

extern "C" void kernel_launch(void* const* d_in, const int* in_sizes, int n_in,
                              void* d_out, int out_size, void* d_ws, size_t ws_size,
                              hipStream_t stream) {
  const float* z = (const float*)d_in[0];
  const float* e = (const float*)d_in[1];
  float* out = (float*)d_out;
  float* sim = out;                                   // [8192,4096]
  float* wout = out + (size_t)M_TOK * N_EXP;          // [8192,1024]

  char* ws = (char*)d_ws;
  u16* Wb  = (u16*)ws;                                // 64 MiB (written after GEMM1)
  u16* zb  = (u16*)ws;                                // 16 MiB, aliases Wb (dead by then)
  u16* eb  = (u16*)(ws + ((size_t)64 << 20));         // 8 MiB
  u16* ebT = (u16*)(ws + ((size_t)72 << 20));         // 8 MiB
  float* z_sq   = (float*)(ws + ((size_t)80 << 20));            // 32 KiB
  float* e_sq   = (float*)(ws + ((size_t)80 << 20) + 32768);    // 16 KiB
  float* rowsum = (float*)(ws + ((size_t)80 << 20) + 49152);    // 32 KiB

  prep_convert<<<M_TOK, 256, 0, stream>>>(z, zb, z_sq);
  prep_convert<<<N_EXP, 256, 0, stream>>>(e, eb, e_sq);
  transpose_bf16<<<dim3(N_EXP / 64, D_DIM / 64), 256, 0, stream>>>(eb, ebT);
  hipMemsetAsync(rowsum, 0, M_TOK * sizeof(float), stream);

  // GEMM1: sim = exp(-(|z|^2+|e|^2-2 z.e)/2), rowsum = sum(exp(sim))
  gemm_bt<1><<<(M_TOK / 128) * (N_EXP / 128), 256, 0, stream>>>(
      zb, eb, M_TOK, N_EXP, D_DIM, sim, N_EXP, z_sq, e_sq, rowsum);

  // weights (bf16)
  weights_kernel<<<(M_TOK * (size_t)N_EXP) / (8 * 256), 256, 0, stream>>>(sim, rowsum, Wb);

  // GEMM2: wout = W @ E   (Bt = E^T, K-contiguous)
  gemm_bt<0><<<(M_TOK / 128) * (D_DIM / 128), 256, 0, stream>>>(
      Wb, ebT, M_TOK, D_DIM, N_EXP, wout, D_DIM, nullptr, nullptr, nullptr);
}

// Round 2
// 217.267 us; speedup vs baseline: 1.0877x; 1.0877x over previous
//
#include <hip/hip_runtime.h>
#include <stdint.h>

// GaussianKernelSimilarity: z[8192,1024] f32, expert_keys[4096,1024] f32
// out0 = exp(-max(|z|^2+|e|^2-2 z.e, 0)/2)  [8192,4096]
// out1 = softmax(out0, axis=-1) @ expert_keys [8192,1024]
//
// Round 2: fuse the weights pass away.
//  - GEMM1 epilogue stores sim (f32, d_out) AND bf16(exp(sim)) -> Wb
//    (unnormalized weights), accumulates rowsum = sum(exp(sim)).
//  - GEMM2 computes U = expsim @ E and scales row m by 1/rowsum[m] in its
//    epilogue (row-scaling commutes through the GEMM).
//  - Fallback to round-1 3-kernel path if ws_size < 96 MiB (zb can no longer
//    alias Wb in the fused path).

#define M_TOK 8192
#define N_EXP 4096
#define D_DIM 1024

typedef __attribute__((ext_vector_type(4))) float f32x4;
typedef __attribute__((ext_vector_type(8))) short short8;
typedef unsigned short u16;
typedef unsigned int u32;

__device__ __forceinline__ u16 f32_to_bf16(float f) {
  u32 u = __builtin_bit_cast(u32, f);
  u += 0x7fff + ((u >> 16) & 1);   // round-to-nearest-even
  return (u16)(u >> 16);
}

__device__ __forceinline__ void async16(const void* g, void* l) {
  __builtin_amdgcn_global_load_lds((__attribute__((address_space(1))) void*)(g),
                                   (__attribute__((address_space(3))) void*)(l),
                                   16, 0, 0);
}

// ---- prep: f32 -> bf16 row convert + row sum of squares -------------------
__global__ __launch_bounds__(256) void prep_convert(const float* __restrict__ src,
                                                    u16* __restrict__ dst,
                                                    float* __restrict__ sq) {
  int row = blockIdx.x;
  int t = threadIdx.x;                       // 256 threads, 4 elems each (D=1024)
  const float4 v = ((const float4*)(src + (size_t)row * D_DIM))[t];
  ushort4 h;
  h.x = f32_to_bf16(v.x); h.y = f32_to_bf16(v.y);
  h.z = f32_to_bf16(v.z); h.w = f32_to_bf16(v.w);
  ((ushort4*)(dst + (size_t)row * D_DIM))[t] = h;
  float p = v.x * v.x + v.y * v.y + v.z * v.z + v.w * v.w;
#pragma unroll
  for (int off = 1; off < 64; off <<= 1) p += __shfl_xor(p, off, 64);
  __shared__ float partial[4];
  if ((t & 63) == 0) partial[t >> 6] = p;
  __syncthreads();
  if (t == 0) sq[row] = partial[0] + partial[1] + partial[2] + partial[3];
}

// ---- bf16 transpose: eb[4096][1024] -> ebT[1024][4096] --------------------
__global__ __launch_bounds__(256) void transpose_bf16(const u16* __restrict__ src,
                                                      u16* __restrict__ dst) {
  __shared__ u16 tile[64][65];
  int e0 = blockIdx.x * 64;   // src row block (expert idx)
  int d0 = blockIdx.y * 64;   // src col block (dim idx)
  int t = threadIdx.x;
  int lr = t >> 4;            // 0..15
  int lc = (t & 15) * 4;      // 0..60
#pragma unroll
  for (int r8 = 0; r8 < 4; ++r8) {
    int row = lr + r8 * 16;
    ushort4 v = *(const ushort4*)(src + (size_t)(e0 + row) * D_DIM + d0 + lc);
    tile[row][lc + 0] = v.x; tile[row][lc + 1] = v.y;
    tile[row][lc + 2] = v.z; tile[row][lc + 3] = v.w;
  }
  __syncthreads();
#pragma unroll
  for (int r8 = 0; r8 < 4; ++r8) {
    int dl = lr + r8 * 16;
    ushort4 v;
    v.x = tile[lc + 0][dl]; v.y = tile[lc + 1][dl];
    v.z = tile[lc + 2][dl]; v.w = tile[lc + 3][dl];
    *(ushort4*)(dst + (size_t)(d0 + dl) * N_EXP + e0 + lc) = v;
  }
}

// ---- gemm_bt: C[M,N] = A[M,K] * Bt[N,K]^T, bf16 MFMA 16x16x32 -------------
// 128x128 tile, BK=64, 4 waves (2x2), 64x64 per wave, 4x4 fragments.
// LDS XOR-swizzle on the READ side; global SOURCE pre-swizzled with the same
// involution so global_load_lds (linear dest) lands data where reads expect.
// EPI=1: similarity epilogue: sim=exp(-d2/2) -> out (f32); es=exp(sim) ->
//        wb (bf16, if non-null); rowsum += es (atomics).
// EPI=0: store acc (scaled by 1/scale[row] if scale non-null).
template <int EPI>
__global__ __launch_bounds__(256) void gemm_bt(const u16* __restrict__ A,
                                               const u16* __restrict__ Bt,
                                               int Mdim, int Ndim, int Kdim,
                                               float* __restrict__ out, int ldo,
                                               const float* __restrict__ a_sq,
                                               const float* __restrict__ b_sq,
                                               float* __restrict__ rowsum,
                                               u16* __restrict__ wb,
                                               const float* __restrict__ scale) {
  constexpr int BM = 128, BN = 128, BK = 64;
  __shared__ __align__(16) u16 smA[BM * BK];
  __shared__ __align__(16) u16 smB[BN * BK];

  const int nTilesN = Ndim / BN;
  const int nwg = (Mdim / BM) * nTilesN;
  const int cpx = nwg >> 3;                    // nwg % 8 == 0 for both gemms
  const int wg = blockIdx.x;
  const int swz = (wg & 7) * cpx + (wg >> 3);  // XCD-aware swizzle
  const int m0 = (swz / nTilesN) * BM;
  const int n0 = (swz % nTilesN) * BN;

  const int t = threadIdx.x;
  const int l = t & 63;
  const int w = t >> 6;          // wave 0..3
  const int wr = w >> 1, wc = w & 1;

  // staging: issue s covers LDS rows [s*8, s*8+8); lane l -> row s*8 + l/8,
  // source col pre-swizzled: 8*((l%8) ^ (l/8)) elements.
  const int lr8 = l >> 3;
  const int cswz = (((l & 7) ^ lr8) << 3);

  f32x4 acc[4][4];
#pragma unroll
  for (int i = 0; i < 4; ++i)
#pragma unroll
    for (int j = 0; j < 4; ++j) acc[i][j] = (f32x4){0.f, 0.f, 0.f, 0.f};

  for (int k0 = 0; k0 < Kdim; k0 += BK) {
    __syncthreads();
#pragma unroll
    for (int i = 0; i < 4; ++i) {
      int s = i * 4 + w;
      int row = s * 8 + lr8;
      async16(A + (size_t)(m0 + row) * Kdim + k0 + cswz, smA + s * 512);
    }
#pragma unroll
    for (int i = 0; i < 4; ++i) {
      int s = i * 4 + w;
      int row = s * 8 + lr8;
      async16(Bt + (size_t)(n0 + row) * Kdim + k0 + cswz, smB + s * 512);
    }
    __syncthreads();   // compiler drains vmcnt(0) before barrier

#pragma unroll
    for (int ks = 0; ks < 2; ++ks) {
      short8 af[4], bf[4];
      const int lrow = l & 15;
      const int kb = ks * 64 + ((l >> 4) << 4);   // byte offset in row
#pragma unroll
      for (int mi = 0; mi < 4; ++mi) {
        int row = wr * 64 + mi * 16 + lrow;
        int addr = row * 128 + (kb ^ ((row & 7) << 4));
        af[mi] = *(const short8*)(smA + (addr >> 1));
      }
#pragma unroll
      for (int ni = 0; ni < 4; ++ni) {
        int row = wc * 64 + ni * 16 + lrow;
        int addr = row * 128 + (kb ^ ((row & 7) << 4));
        bf[ni] = *(const short8*)(smB + (addr >> 1));
      }
#pragma unroll
      for (int mi = 0; mi < 4; ++mi)
#pragma unroll
        for (int ni = 0; ni < 4; ++ni)
          acc[mi][ni] = __builtin_amdgcn_mfma_f32_16x16x32_bf16(
              af[mi], bf[ni], acc[mi][ni], 0, 0, 0);
    }
  }

  // epilogue: C/D layout col = lane&15, row = (lane>>4)*4 + reg  [m89]
  const int lrow16 = l & 15;
  const int rgrp = l >> 4;
  if (EPI == 1) {
    float eq[4];
#pragma unroll
    for (int ni = 0; ni < 4; ++ni)
      eq[ni] = b_sq[n0 + wc * 64 + ni * 16 + lrow16];
#pragma unroll
    for (int mi = 0; mi < 4; ++mi) {
#pragma unroll
      for (int r = 0; r < 4; ++r) {
        int grow = m0 + wr * 64 + mi * 16 + rgrp * 4 + r;
        float zq = a_sq[grow];
        float esum = 0.f;
#pragma unroll
        for (int ni = 0; ni < 4; ++ni) {
          int gcol = n0 + wc * 64 + ni * 16 + lrow16;
          float dist2 = fmaxf(zq + eq[ni] - 2.0f * acc[mi][ni][r], 0.0f);
          float sim = __expf(-0.5f * dist2);
          out[(size_t)grow * ldo + gcol] = sim;
          float es = __expf(sim);   // softmax numerator (sim in [0,1], no max-sub needed)
          if (wb) wb[(size_t)grow * ldo + gcol] = f32_to_bf16(es);
          esum += es;
        }
#pragma unroll
        for (int off = 1; off < 16; off <<= 1) esum += __shfl_xor(esum, off, 64);
        if (lrow16 == 0) atomicAdd(&rowsum[grow], esum);
      }
    }
  } else {
#pragma unroll
    for (int mi = 0; mi < 4; ++mi)
#pragma unroll
      for (int r = 0; r < 4; ++r) {
        int grow = m0 + wr * 64 + mi * 16 + rgrp * 4 + r;
        float s = scale ? (1.0f / scale[grow]) : 1.0f;
#pragma unroll
        for (int ni = 0; ni < 4; ++ni) {
          int gcol = n0 + wc * 64 + ni * 16 + lrow16;
          out[(size_t)grow * ldo + gcol] = acc[mi][ni][r] * s;
        }
      }
  }
}

// ---- weights (fallback path only): w = exp(sim)/rowsum, store bf16 --------
__global__ __launch_bounds__(256) void weights_kernel(const float* __restrict__ sim,
                                                      const float* __restrict__ rowsum,
                                                      u16* __restrict__ wb) {
  size_t i = ((size_t)blockIdx.x * 256 + threadIdx.x) * 8;
  int row = (int)(i >> 12);                  // / 4096
  float inv = 1.0f / rowsum[row];
  float4 a = *(const float4*)(sim + i);
  float4 b = *(const float4*)(sim + i + 4);
  u32 w0 = (u32)f32_to_bf16(__expf(a.x) * inv) | ((u32)f32_to_bf16(__expf(a.y) * inv) << 16);
  u32 w1 = (u32)f32_to_bf16(__expf(a.z) * inv) | ((u32)f32_to_bf16(__expf(a.w) * inv) << 16);
  u32 w2 = (u32)f32_to_bf16(__expf(b.x) * inv) | ((u32)f32_to_bf16(__expf(b.y) * inv) << 16);
  u32 w3 = (u32)f32_to_bf16(__expf(b.z) * inv) | ((u32)f32_to_bf16(__expf(b.w) * inv) << 16);
  uint4 o; o.x = w0; o.y = w1; o.z = w2; o.w = w3;
  *(uint4*)(wb + i) = o;
}

extern "C" void kernel_launch(void* const* d_in, const int* in_sizes, int n_in,
                              void* d_out, int out_size, void* d_ws, size_t ws_size,
                              hipStream_t stream) {
  const float* z = (const float*)d_in[0];
  const float* e = (const float*)d_in[1];
  float* out = (float*)d_out;
  float* sim = out;                                   // [8192,4096]
  float* wout = out + (size_t)M_TOK * N_EXP;          // [8192,1024]

  char* ws = (char*)d_ws;
  const size_t MB = (size_t)1 << 20;
  const bool fused = ws_size >= 96 * MB + 80 * 1024;

  if (fused) {
    // layout: zb | eb | ebT | Wb | z_sq | e_sq | rowsum  (no aliasing)
    u16* zb  = (u16*)ws;                              // 16 MiB
    u16* eb  = (u16*)(ws + 16 * MB);                  // 8 MiB
    u16* ebT = (u16*)(ws + 24 * MB);                  // 8 MiB
    u16* Wb  = (u16*)(ws + 32 * MB);                  // 64 MiB (unnormalized expsim)
    float* z_sq   = (float*)(ws + 96 * MB);           // 32 KiB
    float* e_sq   = (float*)(ws + 96 * MB + 32768);   // 16 KiB
    float* rowsum = (float*)(ws + 96 * MB + 49152);   // 32 KiB

    prep_convert<<<M_TOK, 256, 0, stream>>>(z, zb, z_sq);
    prep_convert<<<N_EXP, 256, 0, stream>>>(e, eb, e_sq);
    transpose_bf16<<<dim3(N_EXP / 64, D_DIM / 64), 256, 0, stream>>>(eb, ebT);
    hipMemsetAsync(rowsum, 0, M_TOK * sizeof(float), stream);

    // GEMM1: sim -> out, bf16(exp(sim)) -> Wb, rowsum accumulated
    gemm_bt<1><<<(M_TOK / 128) * (N_EXP / 128), 256, 0, stream>>>(
        zb, eb, M_TOK, N_EXP, D_DIM, sim, N_EXP, z_sq, e_sq, rowsum, Wb, nullptr);

    // GEMM2: wout = (expsim @ E) / rowsum[row]
    gemm_bt<0><<<(M_TOK / 128) * (D_DIM / 128), 256, 0, stream>>>(
        Wb, ebT, M_TOK, D_DIM, N_EXP, wout, D_DIM, nullptr, nullptr, nullptr,
        nullptr, rowsum);
  } else {
    // round-1 fallback: zb aliases Wb, separate weights pass
    u16* Wb  = (u16*)ws;                              // 64 MiB
    u16* zb  = (u16*)ws;                              // 16 MiB, aliases Wb
    u16* eb  = (u16*)(ws + 64 * MB);                  // 8 MiB
    u16* ebT = (u16*)(ws + 72 * MB);                  // 8 MiB
    float* z_sq   = (float*)(ws + 80 * MB);
    float* e_sq   = (float*)(ws + 80 * MB + 32768);
    float* rowsum = (float*)(ws + 80 * MB + 49152);

    prep_convert<<<M_TOK, 256, 0, stream>>>(z, zb, z_sq);
    prep_convert<<<N_EXP, 256, 0, stream>>>(e, eb, e_sq);
    transpose_bf16<<<dim3(N_EXP / 64, D_DIM / 64), 256, 0, stream>>>(eb, ebT);
    hipMemsetAsync(rowsum, 0, M_TOK * sizeof(float), stream);

    gemm_bt<1><<<(M_TOK / 128) * (N_EXP / 128), 256, 0, stream>>>(
        zb, eb, M_TOK, N_EXP, D_DIM, sim, N_EXP, z_sq, e_sq, rowsum, nullptr, nullptr);

    weights_kernel<<<(M_TOK * (size_t)N_EXP) / (8 * 256), 256, 0, stream>>>(sim, rowsum, Wb);

    gemm_bt<0><<<(M_TOK / 128) * (D_DIM / 128), 256, 0, stream>>>(
        Wb, ebT, M_TOK, D_DIM, N_EXP, wout, D_DIM, nullptr, nullptr, nullptr,
        nullptr, nullptr);
  }
}

// Round 4
// 211.577 us; speedup vs baseline: 1.1169x; 1.0269x over previous
//
#include <hip/hip_runtime.h>
#include <stdint.h>

// GaussianKernelSimilarity: z[8192,1024] f32, expert_keys[4096,1024] f32
// out0 = exp(-max(|z|^2+|e|^2-2 z.e, 0)/2)  [8192,4096]
// out1 = softmax(out0, axis=-1) @ expert_keys [8192,1024]
//
// Round 4 (= round 3 + compile fix): swapped-operand epilogue.
// mfma(bf, af, acc) transposes C/D so each lane holds 4 CONSECUTIVE N-columns
// per fragment (m-row = lane&15 + mi*16). Epilogue becomes f32x4/ushort4
// stores (1KB per wave-instr), rowsum reduction is lane-local + 2 shuffles.
// sim store is non-temporal via ext_vector f32x4 (HIP float4 class rejected
// by __builtin_nontemporal_store).

#define M_TOK 8192
#define N_EXP 4096
#define D_DIM 1024

typedef __attribute__((ext_vector_type(4))) float f32x4;
typedef __attribute__((ext_vector_type(8))) short short8;
typedef unsigned short u16;
typedef unsigned int u32;

__device__ __forceinline__ u16 f32_to_bf16(float f) {
  u32 u = __builtin_bit_cast(u32, f);
  u += 0x7fff + ((u >> 16) & 1);   // round-to-nearest-even
  return (u16)(u >> 16);
}

__device__ __forceinline__ void async16(const void* g, void* l) {
  __builtin_amdgcn_global_load_lds((__attribute__((address_space(1))) void*)(g),
                                   (__attribute__((address_space(3))) void*)(l),
                                   16, 0, 0);
}

// ---- prep: f32 -> bf16 row convert + row sum of squares -------------------
__global__ __launch_bounds__(256) void prep_convert(const float* __restrict__ src,
                                                    u16* __restrict__ dst,
                                                    float* __restrict__ sq) {
  int row = blockIdx.x;
  int t = threadIdx.x;                       // 256 threads, 4 elems each (D=1024)
  const float4 v = ((const float4*)(src + (size_t)row * D_DIM))[t];
  ushort4 h;
  h.x = f32_to_bf16(v.x); h.y = f32_to_bf16(v.y);
  h.z = f32_to_bf16(v.z); h.w = f32_to_bf16(v.w);
  ((ushort4*)(dst + (size_t)row * D_DIM))[t] = h;
  float p = v.x * v.x + v.y * v.y + v.z * v.z + v.w * v.w;
#pragma unroll
  for (int off = 1; off < 64; off <<= 1) p += __shfl_xor(p, off, 64);
  __shared__ float partial[4];
  if ((t & 63) == 0) partial[t >> 6] = p;
  __syncthreads();
  if (t == 0) sq[row] = partial[0] + partial[1] + partial[2] + partial[3];
}

// ---- bf16 transpose: eb[4096][1024] -> ebT[1024][4096] --------------------
__global__ __launch_bounds__(256) void transpose_bf16(const u16* __restrict__ src,
                                                      u16* __restrict__ dst) {
  __shared__ u16 tile[64][65];
  int e0 = blockIdx.x * 64;   // src row block (expert idx)
  int d0 = blockIdx.y * 64;   // src col block (dim idx)
  int t = threadIdx.x;
  int lr = t >> 4;            // 0..15
  int lc = (t & 15) * 4;      // 0..60
#pragma unroll
  for (int r8 = 0; r8 < 4; ++r8) {
    int row = lr + r8 * 16;
    ushort4 v = *(const ushort4*)(src + (size_t)(e0 + row) * D_DIM + d0 + lc);
    tile[row][lc + 0] = v.x; tile[row][lc + 1] = v.y;
    tile[row][lc + 2] = v.z; tile[row][lc + 3] = v.w;
  }
  __syncthreads();
#pragma unroll
  for (int r8 = 0; r8 < 4; ++r8) {
    int dl = lr + r8 * 16;
    ushort4 v;
    v.x = tile[lc + 0][dl]; v.y = tile[lc + 1][dl];
    v.z = tile[lc + 2][dl]; v.w = tile[lc + 3][dl];
    *(ushort4*)(dst + (size_t)(d0 + dl) * N_EXP + e0 + lc) = v;
  }
}

// ---- gemm_bt: C[M,N] = A[M,K] * Bt[N,K]^T, bf16 MFMA 16x16x32 -------------
// 128x128 tile, BK=64, 4 waves (2x2), 64x64 per wave, 4x4 fragments.
// LDS XOR-swizzle on the READ side; global SOURCE pre-swizzled with the same
// involution so global_load_lds (linear dest) lands data where reads expect.
// SWAPPED operands: mfma(bf, af, acc) -> D transposed vs classic:
//   M-row = lane&15 (+ mi*16 + wr*64)
//   N-col = (lane>>4)*4 + reg (+ ni*16 + wc*64)
// so each lane holds 4 consecutive N-columns per fragment -> f32x4 stores.
// EPI=1: sim=exp(-d2/2) -> out (f32, nontemporal); bf16(exp(sim)) -> wb;
//        rowsum += sum(exp(sim)) (2 shuffles + atomic per mi).
// EPI=0: store acc (scaled by 1/scale[row] if scale non-null).
template <int EPI>
__global__ __launch_bounds__(256) void gemm_bt(const u16* __restrict__ A,
                                               const u16* __restrict__ Bt,
                                               int Mdim, int Ndim, int Kdim,
                                               float* __restrict__ out, int ldo,
                                               const float* __restrict__ a_sq,
                                               const float* __restrict__ b_sq,
                                               float* __restrict__ rowsum,
                                               u16* __restrict__ wb,
                                               const float* __restrict__ scale) {
  constexpr int BM = 128, BN = 128, BK = 64;
  __shared__ __align__(16) u16 smA[BM * BK];
  __shared__ __align__(16) u16 smB[BN * BK];

  const int nTilesN = Ndim / BN;
  const int nwg = (Mdim / BM) * nTilesN;
  const int cpx = nwg >> 3;                    // nwg % 8 == 0 for both gemms
  const int wg = blockIdx.x;
  const int swz = (wg & 7) * cpx + (wg >> 3);  // XCD-aware swizzle
  const int m0 = (swz / nTilesN) * BM;
  const int n0 = (swz % nTilesN) * BN;

  const int t = threadIdx.x;
  const int l = t & 63;
  const int w = t >> 6;          // wave 0..3
  const int wr = w >> 1, wc = w & 1;

  // staging: issue s covers LDS rows [s*8, s*8+8); lane l -> row s*8 + l/8,
  // source col pre-swizzled: 8*((l%8) ^ (l/8)) elements.
  const int lr8 = l >> 3;
  const int cswz = (((l & 7) ^ lr8) << 3);

  f32x4 acc[4][4];
#pragma unroll
  for (int i = 0; i < 4; ++i)
#pragma unroll
    for (int j = 0; j < 4; ++j) acc[i][j] = (f32x4){0.f, 0.f, 0.f, 0.f};

  for (int k0 = 0; k0 < Kdim; k0 += BK) {
    __syncthreads();
#pragma unroll
    for (int i = 0; i < 4; ++i) {
      int s = i * 4 + w;
      int row = s * 8 + lr8;
      async16(A + (size_t)(m0 + row) * Kdim + k0 + cswz, smA + s * 512);
    }
#pragma unroll
    for (int i = 0; i < 4; ++i) {
      int s = i * 4 + w;
      int row = s * 8 + lr8;
      async16(Bt + (size_t)(n0 + row) * Kdim + k0 + cswz, smB + s * 512);
    }
    __syncthreads();   // compiler drains vmcnt(0) before barrier

#pragma unroll
    for (int ks = 0; ks < 2; ++ks) {
      short8 af[4], bf[4];
      const int lrow = l & 15;
      const int kb = ks * 64 + ((l >> 4) << 4);   // byte offset in row
#pragma unroll
      for (int mi = 0; mi < 4; ++mi) {
        int row = wr * 64 + mi * 16 + lrow;
        int addr = row * 128 + (kb ^ ((row & 7) << 4));
        af[mi] = *(const short8*)(smA + (addr >> 1));
      }
#pragma unroll
      for (int ni = 0; ni < 4; ++ni) {
        int row = wc * 64 + ni * 16 + lrow;
        int addr = row * 128 + (kb ^ ((row & 7) << 4));
        bf[ni] = *(const short8*)(smB + (addr >> 1));
      }
      // swapped operands: mfma(bf, af) => per-lane m = lane&15,
      // n = (lane>>4)*4 + reg.
#pragma unroll
      for (int mi = 0; mi < 4; ++mi)
#pragma unroll
        for (int ni = 0; ni < 4; ++ni)
          acc[mi][ni] = __builtin_amdgcn_mfma_f32_16x16x32_bf16(
              bf[ni], af[mi], acc[mi][ni], 0, 0, 0);
    }
  }

  // epilogue (swapped layout): m = lane&15 (+mi*16+wr*64),
  //                            n = (lane>>4)*4 + r (+ni*16+wc*64)
  const int lcol = l & 15;
  const int rgrp = l >> 4;
  if (EPI == 1) {
#pragma unroll
    for (int mi = 0; mi < 4; ++mi) {
      int grow = m0 + wr * 64 + mi * 16 + lcol;
      float zq = a_sq[grow];
      float esum = 0.f;
#pragma unroll
      for (int ni = 0; ni < 4; ++ni) {
        int ncol = n0 + wc * 64 + ni * 16 + rgrp * 4;
        f32x4 simv;
        ushort4 wv;
#pragma unroll
        for (int r = 0; r < 4; ++r) {
          float eq = b_sq[ncol + r];
          float dist2 = fmaxf(zq + eq - 2.0f * acc[mi][ni][r], 0.0f);
          float sim = __expf(-0.5f * dist2);
          simv[r] = sim;
          float es = __expf(sim);   // softmax numerator (sim in [0,1], no max-sub)
          (&wv.x)[r] = f32_to_bf16(es);
          esum += es;
        }
        __builtin_nontemporal_store(simv, (f32x4*)(out + (size_t)grow * ldo + ncol));
        if (wb) *(ushort4*)(wb + (size_t)grow * ldo + ncol) = wv;
      }
      // lanes l, l+16, l+32, l+48 share grow -> butterfly over bits 4,5
      esum += __shfl_xor(esum, 16, 64);
      esum += __shfl_xor(esum, 32, 64);
      if (rgrp == 0) atomicAdd(&rowsum[grow], esum);
    }
  } else {
#pragma unroll
    for (int mi = 0; mi < 4; ++mi) {
      int grow = m0 + wr * 64 + mi * 16 + lcol;
      float s = scale ? (1.0f / scale[grow]) : 1.0f;
#pragma unroll
      for (int ni = 0; ni < 4; ++ni) {
        int ncol = n0 + wc * 64 + ni * 16 + rgrp * 4;
        f32x4 v = acc[mi][ni] * s;
        *(f32x4*)(out + (size_t)grow * ldo + ncol) = v;
      }
    }
  }
}

// ---- weights (fallback path only): w = exp(sim)/rowsum, store bf16 --------
__global__ __launch_bounds__(256) void weights_kernel(const float* __restrict__ sim,
                                                      const float* __restrict__ rowsum,
                                                      u16* __restrict__ wb) {
  size_t i = ((size_t)blockIdx.x * 256 + threadIdx.x) * 8;
  int row = (int)(i >> 12);                  // / 4096
  float inv = 1.0f / rowsum[row];
  float4 a = *(const float4*)(sim + i);
  float4 b = *(const float4*)(sim + i + 4);
  u32 w0 = (u32)f32_to_bf16(__expf(a.x) * inv) | ((u32)f32_to_bf16(__expf(a.y) * inv) << 16);
  u32 w1 = (u32)f32_to_bf16(__expf(a.z) * inv) | ((u32)f32_to_bf16(__expf(a.w) * inv) << 16);
  u32 w2 = (u32)f32_to_bf16(__expf(b.x) * inv) | ((u32)f32_to_bf16(__expf(b.y) * inv) << 16);
  u32 w3 = (u32)f32_to_bf16(__expf(b.z) * inv) | ((u32)f32_to_bf16(__expf(b.w) * inv) << 16);
  uint4 o; o.x = w0; o.y = w1; o.z = w2; o.w = w3;
  *(uint4*)(wb + i) = o;
}

extern "C" void kernel_launch(void* const* d_in, const int* in_sizes, int n_in,
                              void* d_out, int out_size, void* d_ws, size_t ws_size,
                              hipStream_t stream) {
  const float* z = (const float*)d_in[0];
  const float* e = (const float*)d_in[1];
  float* out = (float*)d_out;
  float* sim = out;                                   // [8192,4096]
  float* wout = out + (size_t)M_TOK * N_EXP;          // [8192,1024]

  char* ws = (char*)d_ws;
  const size_t MB = (size_t)1 << 20;
  const bool fused = ws_size >= 96 * MB + 80 * 1024;

  if (fused) {
    // layout: zb | eb | ebT | Wb | z_sq | e_sq | rowsum  (no aliasing)
    u16* zb  = (u16*)ws;                              // 16 MiB
    u16* eb  = (u16*)(ws + 16 * MB);                  // 8 MiB
    u16* ebT = (u16*)(ws + 24 * MB);                  // 8 MiB
    u16* Wb  = (u16*)(ws + 32 * MB);                  // 64 MiB (unnormalized expsim)
    float* z_sq   = (float*)(ws + 96 * MB);           // 32 KiB
    float* e_sq   = (float*)(ws + 96 * MB + 32768);   // 16 KiB
    float* rowsum = (float*)(ws + 96 * MB + 49152);   // 32 KiB

    prep_convert<<<M_TOK, 256, 0, stream>>>(z, zb, z_sq);
    prep_convert<<<N_EXP, 256, 0, stream>>>(e, eb, e_sq);
    transpose_bf16<<<dim3(N_EXP / 64, D_DIM / 64), 256, 0, stream>>>(eb, ebT);
    (void)hipMemsetAsync(rowsum, 0, M_TOK * sizeof(float), stream);

    // GEMM1: sim -> out, bf16(exp(sim)) -> Wb, rowsum accumulated
    gemm_bt<1><<<(M_TOK / 128) * (N_EXP / 128), 256, 0, stream>>>(
        zb, eb, M_TOK, N_EXP, D_DIM, sim, N_EXP, z_sq, e_sq, rowsum, Wb, nullptr);

    // GEMM2: wout = (expsim @ E) / rowsum[row]
    gemm_bt<0><<<(M_TOK / 128) * (D_DIM / 128), 256, 0, stream>>>(
        Wb, ebT, M_TOK, D_DIM, N_EXP, wout, D_DIM, nullptr, nullptr, nullptr,
        nullptr, rowsum);
  } else {
    // fallback: zb aliases Wb, separate weights pass
    u16* Wb  = (u16*)ws;                              // 64 MiB
    u16* zb  = (u16*)ws;                              // 16 MiB, aliases Wb
    u16* eb  = (u16*)(ws + 64 * MB);                  // 8 MiB
    u16* ebT = (u16*)(ws + 72 * MB);                  // 8 MiB
    float* z_sq   = (float*)(ws + 80 * MB);
    float* e_sq   = (float*)(ws + 80 * MB + 32768);
    float* rowsum = (float*)(ws + 80 * MB + 49152);

    prep_convert<<<M_TOK, 256, 0, stream>>>(z, zb, z_sq);
    prep_convert<<<N_EXP, 256, 0, stream>>>(e, eb, e_sq);
    transpose_bf16<<<dim3(N_EXP / 64, D_DIM / 64), 256, 0, stream>>>(eb, ebT);
    (void)hipMemsetAsync(rowsum, 0, M_TOK * sizeof(float), stream);

    gemm_bt<1><<<(M_TOK / 128) * (N_EXP / 128), 256, 0, stream>>>(
        zb, eb, M_TOK, N_EXP, D_DIM, sim, N_EXP, z_sq, e_sq, rowsum, nullptr, nullptr);

    weights_kernel<<<(M_TOK * (size_t)N_EXP) / (8 * 256), 256, 0, stream>>>(sim, rowsum, Wb);

    gemm_bt<0><<<(M_TOK / 128) * (D_DIM / 128), 256, 0, stream>>>(
        Wb, ebT, M_TOK, D_DIM, N_EXP, wout, D_DIM, nullptr, nullptr, nullptr,
        nullptr, nullptr);
  }
}

// Round 5
// 201.100 us; speedup vs baseline: 1.1751x; 1.0521x over previous
//
#include <hip/hip_runtime.h>
#include <stdint.h>

// GaussianKernelSimilarity: z[8192,1024] f32, expert_keys[4096,1024] f32
// out0 = exp(-max(|z|^2+|e|^2-2 z.e, 0)/2)  [8192,4096]
// out1 = softmax(out0, axis=-1) @ expert_keys [8192,1024]
//
// Round 5: double-buffered LDS, T3-minimum schedule (issue next-tile
// global_load_lds BEFORE current tile's ds_read+MFMA; single barrier per
// K-step whose compiler-emitted vmcnt(0)/lgkmcnt(0) drain provides the
// correctness). Removed non-temporal store (raised FETCH 28MB, no win).
// Fused the two prep kernels into one launch. Swapped-operand MFMA layout
// retained (vector f32x4/ushort4 epilogue stores).

#define M_TOK 8192
#define N_EXP 4096
#define D_DIM 1024

typedef __attribute__((ext_vector_type(4))) float f32x4;
typedef __attribute__((ext_vector_type(8))) short short8;
typedef unsigned short u16;
typedef unsigned int u32;

__device__ __forceinline__ u16 f32_to_bf16(float f) {
  u32 u = __builtin_bit_cast(u32, f);
  u += 0x7fff + ((u >> 16) & 1);   // round-to-nearest-even
  return (u16)(u >> 16);
}

__device__ __forceinline__ void async16(const void* g, void* l) {
  __builtin_amdgcn_global_load_lds((__attribute__((address_space(1))) void*)(g),
                                   (__attribute__((address_space(3))) void*)(l),
                                   16, 0, 0);
}

// ---- prep: f32 -> bf16 convert + row |.|^2 for BOTH z and e (one launch) --
__global__ __launch_bounds__(256) void prep_convert2(const float* __restrict__ zsrc,
                                                     const float* __restrict__ esrc,
                                                     u16* __restrict__ zdst,
                                                     u16* __restrict__ edst,
                                                     float* __restrict__ zsq,
                                                     float* __restrict__ esq) {
  int row = blockIdx.x;
  const float* src;
  u16* dst;
  float* sq;
  if (row < M_TOK) {
    src = zsrc + (size_t)row * D_DIM;
    dst = zdst + (size_t)row * D_DIM;
    sq = zsq + row;
  } else {
    int r = row - M_TOK;
    src = esrc + (size_t)r * D_DIM;
    dst = edst + (size_t)r * D_DIM;
    sq = esq + r;
  }
  int t = threadIdx.x;                       // 256 threads, 4 elems each
  const float4 v = ((const float4*)src)[t];
  ushort4 h;
  h.x = f32_to_bf16(v.x); h.y = f32_to_bf16(v.y);
  h.z = f32_to_bf16(v.z); h.w = f32_to_bf16(v.w);
  ((ushort4*)dst)[t] = h;
  float p = v.x * v.x + v.y * v.y + v.z * v.z + v.w * v.w;
#pragma unroll
  for (int off = 1; off < 64; off <<= 1) p += __shfl_xor(p, off, 64);
  __shared__ float partial[4];
  if ((t & 63) == 0) partial[t >> 6] = p;
  __syncthreads();
  if (t == 0) *sq = partial[0] + partial[1] + partial[2] + partial[3];
}

// ---- bf16 transpose: eb[4096][1024] -> ebT[1024][4096] --------------------
__global__ __launch_bounds__(256) void transpose_bf16(const u16* __restrict__ src,
                                                      u16* __restrict__ dst) {
  __shared__ u16 tile[64][65];
  int e0 = blockIdx.x * 64;   // src row block (expert idx)
  int d0 = blockIdx.y * 64;   // src col block (dim idx)
  int t = threadIdx.x;
  int lr = t >> 4;            // 0..15
  int lc = (t & 15) * 4;      // 0..60
#pragma unroll
  for (int r8 = 0; r8 < 4; ++r8) {
    int row = lr + r8 * 16;
    ushort4 v = *(const ushort4*)(src + (size_t)(e0 + row) * D_DIM + d0 + lc);
    tile[row][lc + 0] = v.x; tile[row][lc + 1] = v.y;
    tile[row][lc + 2] = v.z; tile[row][lc + 3] = v.w;
  }
  __syncthreads();
#pragma unroll
  for (int r8 = 0; r8 < 4; ++r8) {
    int dl = lr + r8 * 16;
    ushort4 v;
    v.x = tile[lc + 0][dl]; v.y = tile[lc + 1][dl];
    v.z = tile[lc + 2][dl]; v.w = tile[lc + 3][dl];
    *(ushort4*)(dst + (size_t)(d0 + dl) * N_EXP + e0 + lc) = v;
  }
}

// ---- gemm_bt: C[M,N] = A[M,K] * Bt[N,K]^T, bf16 MFMA 16x16x32 -------------
// 128x128 tile, BK=64, 4 waves (2x2), double-buffered LDS (2x16KB per
// operand). Schedule per K-step: issue next tile's 8 global_load_lds, then
// ds_read+MFMA on current buffer, then ONE __syncthreads (its vmcnt/lgkm
// drain makes the next buffer ready and protects the buffer we'll overwrite
// next step). LDS XOR-swizzle on read; global SOURCE pre-swizzled (m173).
// SWAPPED operands: mfma(bf, af, acc):
//   m-row = lane&15 (+ mi*16 + wr*64), n-col = (lane>>4)*4 + reg (+ni*16+wc*64)
// EPI=1: sim=exp(-d2/2) -> out; bf16(exp(sim)) -> wb; rowsum += sum (atomic).
// EPI=0: store acc * (1/scale[row]).
template <int EPI>
__global__ __launch_bounds__(256) void gemm_bt(const u16* __restrict__ A,
                                               const u16* __restrict__ Bt,
                                               int Mdim, int Ndim, int Kdim,
                                               float* __restrict__ out, int ldo,
                                               const float* __restrict__ a_sq,
                                               const float* __restrict__ b_sq,
                                               float* __restrict__ rowsum,
                                               u16* __restrict__ wb,
                                               const float* __restrict__ scale) {
  constexpr int BM = 128, BN = 128, BK = 64;
  __shared__ __align__(16) u16 smA[2 * BM * BK];   // 32 KiB
  __shared__ __align__(16) u16 smB[2 * BN * BK];   // 32 KiB

  const int nTilesN = Ndim / BN;
  const int nwg = (Mdim / BM) * nTilesN;
  const int cpx = nwg >> 3;                    // nwg % 8 == 0 for both gemms
  const int wg = blockIdx.x;
  const int swz = (wg & 7) * cpx + (wg >> 3);  // XCD-aware swizzle
  const int m0 = (swz / nTilesN) * BM;
  const int n0 = (swz % nTilesN) * BN;

  const int t = threadIdx.x;
  const int l = t & 63;
  const int w = t >> 6;          // wave 0..3
  const int wr = w >> 1, wc = w & 1;

  // staging: issue s covers LDS rows [s*8, s*8+8); lane l -> row s*8 + l/8,
  // source col pre-swizzled: 8*((l%8) ^ (l/8)) elements.
  const int lr8 = l >> 3;
  const int cswz = (((l & 7) ^ lr8) << 3);

  f32x4 acc[4][4];
#pragma unroll
  for (int i = 0; i < 4; ++i)
#pragma unroll
    for (int j = 0; j < 4; ++j) acc[i][j] = (f32x4){0.f, 0.f, 0.f, 0.f};

  const int nIter = Kdim / BK;

  // prologue: stage tile 0 into buffer 0
#pragma unroll
  for (int i = 0; i < 4; ++i) {
    int s = i * 4 + w;
    int row = s * 8 + lr8;
    async16(A + (size_t)(m0 + row) * Kdim + cswz, smA + s * 512);
    async16(Bt + (size_t)(n0 + row) * Kdim + cswz, smB + s * 512);
  }
  __syncthreads();

  int cur = 0;
  for (int it = 0; it < nIter; ++it) {
    // issue next tile's loads into the other buffer (stay in flight during
    // this tile's ds_read + MFMA)
    if (it + 1 < nIter) {
      const int k0 = (it + 1) * BK;
      const int nb = (cur ^ 1) * 8192;
#pragma unroll
      for (int i = 0; i < 4; ++i) {
        int s = i * 4 + w;
        int row = s * 8 + lr8;
        async16(A + (size_t)(m0 + row) * Kdim + k0 + cswz, smA + nb + s * 512);
        async16(Bt + (size_t)(n0 + row) * Kdim + k0 + cswz, smB + nb + s * 512);
      }
    }

    const int cbase = cur * 8192;   // element offset of current buffer
#pragma unroll
    for (int ks = 0; ks < 2; ++ks) {
      short8 af[4], bf[4];
      const int lrow = l & 15;
      const int kb = ks * 64 + ((l >> 4) << 4);   // byte offset in row
#pragma unroll
      for (int mi = 0; mi < 4; ++mi) {
        int row = wr * 64 + mi * 16 + lrow;
        int addr = row * 128 + (kb ^ ((row & 7) << 4));
        af[mi] = *(const short8*)(smA + cbase + (addr >> 1));
      }
#pragma unroll
      for (int ni = 0; ni < 4; ++ni) {
        int row = wc * 64 + ni * 16 + lrow;
        int addr = row * 128 + (kb ^ ((row & 7) << 4));
        bf[ni] = *(const short8*)(smB + cbase + (addr >> 1));
      }
#pragma unroll
      for (int mi = 0; mi < 4; ++mi)
#pragma unroll
        for (int ni = 0; ni < 4; ++ni)
          acc[mi][ni] = __builtin_amdgcn_mfma_f32_16x16x32_bf16(
              bf[ni], af[mi], acc[mi][ni], 0, 0, 0);
    }

    // one barrier per K-step: compiler drains vmcnt(0) (next buffer landed)
    // and lgkmcnt (our reads of cur done) before s_barrier -> safe to swap.
    __syncthreads();
    cur ^= 1;
  }

  // epilogue (swapped layout): m = lane&15 (+mi*16+wr*64),
  //                            n = (lane>>4)*4 + r (+ni*16+wc*64)
  const int lcol = l & 15;
  const int rgrp = l >> 4;
  if (EPI == 1) {
#pragma unroll
    for (int mi = 0; mi < 4; ++mi) {
      int grow = m0 + wr * 64 + mi * 16 + lcol;
      float zq = a_sq[grow];
      float esum = 0.f;
#pragma unroll
      for (int ni = 0; ni < 4; ++ni) {
        int ncol = n0 + wc * 64 + ni * 16 + rgrp * 4;
        f32x4 eqv = *(const f32x4*)(b_sq + ncol);
        f32x4 simv;
        ushort4 wv;
#pragma unroll
        for (int r = 0; r < 4; ++r) {
          float dist2 = fmaxf(zq + eqv[r] - 2.0f * acc[mi][ni][r], 0.0f);
          float sim = __expf(-0.5f * dist2);
          simv[r] = sim;
          float es = __expf(sim);   // softmax numerator (sim in [0,1], no max-sub)
          (&wv.x)[r] = f32_to_bf16(es);
          esum += es;
        }
        *(f32x4*)(out + (size_t)grow * ldo + ncol) = simv;
        if (wb) *(ushort4*)(wb + (size_t)grow * ldo + ncol) = wv;
      }
      // lanes l, l+16, l+32, l+48 share grow -> butterfly over bits 4,5
      esum += __shfl_xor(esum, 16, 64);
      esum += __shfl_xor(esum, 32, 64);
      if (rgrp == 0) atomicAdd(&rowsum[grow], esum);
    }
  } else {
#pragma unroll
    for (int mi = 0; mi < 4; ++mi) {
      int grow = m0 + wr * 64 + mi * 16 + lcol;
      float s = scale ? (1.0f / scale[grow]) : 1.0f;
#pragma unroll
      for (int ni = 0; ni < 4; ++ni) {
        int ncol = n0 + wc * 64 + ni * 16 + rgrp * 4;
        f32x4 v = acc[mi][ni] * s;
        *(f32x4*)(out + (size_t)grow * ldo + ncol) = v;
      }
    }
  }
}

// ---- weights (fallback path only): w = exp(sim)/rowsum, store bf16 --------
__global__ __launch_bounds__(256) void weights_kernel(const float* __restrict__ sim,
                                                      const float* __restrict__ rowsum,
                                                      u16* __restrict__ wb) {
  size_t i = ((size_t)blockIdx.x * 256 + threadIdx.x) * 8;
  int row = (int)(i >> 12);                  // / 4096
  float inv = 1.0f / rowsum[row];
  float4 a = *(const float4*)(sim + i);
  float4 b = *(const float4*)(sim + i + 4);
  u32 w0 = (u32)f32_to_bf16(__expf(a.x) * inv) | ((u32)f32_to_bf16(__expf(a.y) * inv) << 16);
  u32 w1 = (u32)f32_to_bf16(__expf(a.z) * inv) | ((u32)f32_to_bf16(__expf(a.w) * inv) << 16);
  u32 w2 = (u32)f32_to_bf16(__expf(b.x) * inv) | ((u32)f32_to_bf16(__expf(b.y) * inv) << 16);
  u32 w3 = (u32)f32_to_bf16(__expf(b.z) * inv) | ((u32)f32_to_bf16(__expf(b.w) * inv) << 16);
  uint4 o; o.x = w0; o.y = w1; o.z = w2; o.w = w3;
  *(uint4*)(wb + i) = o;
}

extern "C" void kernel_launch(void* const* d_in, const int* in_sizes, int n_in,
                              void* d_out, int out_size, void* d_ws, size_t ws_size,
                              hipStream_t stream) {
  const float* z = (const float*)d_in[0];
  const float* e = (const float*)d_in[1];
  float* out = (float*)d_out;
  float* sim = out;                                   // [8192,4096]
  float* wout = out + (size_t)M_TOK * N_EXP;          // [8192,1024]

  char* ws = (char*)d_ws;
  const size_t MB = (size_t)1 << 20;
  const bool fused = ws_size >= 96 * MB + 80 * 1024;

  if (fused) {
    // layout: zb | eb | ebT | Wb | z_sq | e_sq | rowsum  (no aliasing)
    u16* zb  = (u16*)ws;                              // 16 MiB
    u16* eb  = (u16*)(ws + 16 * MB);                  // 8 MiB
    u16* ebT = (u16*)(ws + 24 * MB);                  // 8 MiB
    u16* Wb  = (u16*)(ws + 32 * MB);                  // 64 MiB (unnormalized expsim)
    float* z_sq   = (float*)(ws + 96 * MB);           // 32 KiB
    float* e_sq   = (float*)(ws + 96 * MB + 32768);   // 16 KiB
    float* rowsum = (float*)(ws + 96 * MB + 49152);   // 32 KiB

    prep_convert2<<<M_TOK + N_EXP, 256, 0, stream>>>(z, e, zb, eb, z_sq, e_sq);
    transpose_bf16<<<dim3(N_EXP / 64, D_DIM / 64), 256, 0, stream>>>(eb, ebT);
    (void)hipMemsetAsync(rowsum, 0, M_TOK * sizeof(float), stream);

    // GEMM1: sim -> out, bf16(exp(sim)) -> Wb, rowsum accumulated
    gemm_bt<1><<<(M_TOK / 128) * (N_EXP / 128), 256, 0, stream>>>(
        zb, eb, M_TOK, N_EXP, D_DIM, sim, N_EXP, z_sq, e_sq, rowsum, Wb, nullptr);

    // GEMM2: wout = (expsim @ E) / rowsum[row]
    gemm_bt<0><<<(M_TOK / 128) * (D_DIM / 128), 256, 0, stream>>>(
        Wb, ebT, M_TOK, D_DIM, N_EXP, wout, D_DIM, nullptr, nullptr, nullptr,
        nullptr, rowsum);
  } else {
    // fallback: zb aliases Wb, separate weights pass
    u16* Wb  = (u16*)ws;                              // 64 MiB
    u16* zb  = (u16*)ws;                              // 16 MiB, aliases Wb
    u16* eb  = (u16*)(ws + 64 * MB);                  // 8 MiB
    u16* ebT = (u16*)(ws + 72 * MB);                  // 8 MiB
    float* z_sq   = (float*)(ws + 80 * MB);
    float* e_sq   = (float*)(ws + 80 * MB + 32768);
    float* rowsum = (float*)(ws + 80 * MB + 49152);

    prep_convert2<<<M_TOK + N_EXP, 256, 0, stream>>>(z, e, zb, eb, z_sq, e_sq);
    transpose_bf16<<<dim3(N_EXP / 64, D_DIM / 64), 256, 0, stream>>>(eb, ebT);
    (void)hipMemsetAsync(rowsum, 0, M_TOK * sizeof(float), stream);

    gemm_bt<1><<<(M_TOK / 128) * (N_EXP / 128), 256, 0, stream>>>(
        zb, eb, M_TOK, N_EXP, D_DIM, sim, N_EXP, z_sq, e_sq, rowsum, nullptr, nullptr);

    weights_kernel<<<(M_TOK * (size_t)N_EXP) / (8 * 256), 256, 0, stream>>>(sim, rowsum, Wb);

    gemm_bt<0><<<(M_TOK / 128) * (D_DIM / 128), 256, 0, stream>>>(
        Wb, ebT, M_TOK, D_DIM, N_EXP, wout, D_DIM, nullptr, nullptr, nullptr,
        nullptr, nullptr);
  }
}

// Round 6
// 191.201 us; speedup vs baseline: 1.2359x; 1.0518x over previous
//
#include <hip/hip_runtime.h>
#include <stdint.h>

// GaussianKernelSimilarity: z[8192,1024] f32, expert_keys[4096,1024] f32
// out0 = exp(-max(|z|^2+|e|^2-2 z.e, 0)/2)  [8192,4096]
// out1 = softmax(out0, axis=-1) @ expert_keys [8192,1024]
//
// Round 6: GEMM1 ported to the 256x256 8-phase schedule (T2+T3+T4+T5):
//  - 512 threads = 8 waves (2M x 4N), per-wave 128x64 output, BK=64
//  - LDS 128 KiB: [2 buf][2 half][128x64] for A and B
//  - per K-tile 4 phases: {ds_read subtile; stage 1 half-tile; barrier;
//    lgkmcnt(0)+sched_barrier; setprio(1); 16 MFMA; setprio(0); barrier}
//  - counted s_waitcnt vmcnt(4) once per K-tile (never 0 in steady state).
//    Stagger: A(u+1) staged at P1/P2 (into other buf, consumed at u-1 P3),
//    B(u+2) staged at P3/P4 (into current buf's B, consumed by P2).
// GEMM2 keeps the 128x128 dbuf kernel (8-phase 256 tile would give only 128
// blocks on 256 CUs for N=1024).

#define M_TOK 8192
#define N_EXP 4096
#define D_DIM 1024

typedef __attribute__((ext_vector_type(4))) float f32x4;
typedef __attribute__((ext_vector_type(8))) short short8;
typedef unsigned short u16;
typedef unsigned int u32;

__device__ __forceinline__ u16 f32_to_bf16(float f) {
  u32 u = __builtin_bit_cast(u32, f);
  u += 0x7fff + ((u >> 16) & 1);   // round-to-nearest-even
  return (u16)(u >> 16);
}

__device__ __forceinline__ void async16(const void* g, void* l) {
  __builtin_amdgcn_global_load_lds((__attribute__((address_space(1))) void*)(g),
                                   (__attribute__((address_space(3))) void*)(l),
                                   16, 0, 0);
}

// ---- prep: f32 -> bf16 convert + row |.|^2 for BOTH z and e (one launch) --
__global__ __launch_bounds__(256) void prep_convert2(const float* __restrict__ zsrc,
                                                     const float* __restrict__ esrc,
                                                     u16* __restrict__ zdst,
                                                     u16* __restrict__ edst,
                                                     float* __restrict__ zsq,
                                                     float* __restrict__ esq) {
  int row = blockIdx.x;
  const float* src;
  u16* dst;
  float* sq;
  if (row < M_TOK) {
    src = zsrc + (size_t)row * D_DIM;
    dst = zdst + (size_t)row * D_DIM;
    sq = zsq + row;
  } else {
    int r = row - M_TOK;
    src = esrc + (size_t)r * D_DIM;
    dst = edst + (size_t)r * D_DIM;
    sq = esq + r;
  }
  int t = threadIdx.x;                       // 256 threads, 4 elems each
  const float4 v = ((const float4*)src)[t];
  ushort4 h;
  h.x = f32_to_bf16(v.x); h.y = f32_to_bf16(v.y);
  h.z = f32_to_bf16(v.z); h.w = f32_to_bf16(v.w);
  ((ushort4*)dst)[t] = h;
  float p = v.x * v.x + v.y * v.y + v.z * v.z + v.w * v.w;
#pragma unroll
  for (int off = 1; off < 64; off <<= 1) p += __shfl_xor(p, off, 64);
  __shared__ float partial[4];
  if ((t & 63) == 0) partial[t >> 6] = p;
  __syncthreads();
  if (t == 0) *sq = partial[0] + partial[1] + partial[2] + partial[3];
}

// ---- bf16 transpose: eb[4096][1024] -> ebT[1024][4096] --------------------
__global__ __launch_bounds__(256) void transpose_bf16(const u16* __restrict__ src,
                                                      u16* __restrict__ dst) {
  __shared__ u16 tile[64][65];
  int e0 = blockIdx.x * 64;
  int d0 = blockIdx.y * 64;
  int t = threadIdx.x;
  int lr = t >> 4;
  int lc = (t & 15) * 4;
#pragma unroll
  for (int r8 = 0; r8 < 4; ++r8) {
    int row = lr + r8 * 16;
    ushort4 v = *(const ushort4*)(src + (size_t)(e0 + row) * D_DIM + d0 + lc);
    tile[row][lc + 0] = v.x; tile[row][lc + 1] = v.y;
    tile[row][lc + 2] = v.z; tile[row][lc + 3] = v.w;
  }
  __syncthreads();
#pragma unroll
  for (int r8 = 0; r8 < 4; ++r8) {
    int dl = lr + r8 * 16;
    ushort4 v;
    v.x = tile[lc + 0][dl]; v.y = tile[lc + 1][dl];
    v.z = tile[lc + 2][dl]; v.w = tile[lc + 3][dl];
    *(ushort4*)(dst + (size_t)(d0 + dl) * N_EXP + e0 + lc) = v;
  }
}

// ============================ 8-phase 256x256 ==============================
__device__ __forceinline__ short8 lds_frag(const u16* base, int rh, int kbyte) {
  int ab = rh * 128 + (kbyte ^ ((rh & 7) << 4));
  return *(const short8*)((const char*)base + ab);
}

template <int MOFF, int NOFF>
__device__ __forceinline__ void mfma_q(f32x4 (&acc)[8][4], short8 (&af)[4][2],
                                       short8 (&bf)[4][2]) {
#pragma unroll
  for (int mi = 0; mi < 4; ++mi)
#pragma unroll
    for (int ni = 0; ni < 2; ++ni)
#pragma unroll
      for (int ks = 0; ks < 2; ++ks)
        acc[MOFF + mi][NOFF + ni] = __builtin_amdgcn_mfma_f32_16x16x32_bf16(
            bf[NOFF + ni][ks], af[mi][ks], acc[MOFF + mi][NOFF + ni], 0, 0, 0);
}

#define BAR() __builtin_amdgcn_s_barrier()
#define WAIT_LGKM0() do { asm volatile("s_waitcnt lgkmcnt(0)" ::: "memory"); \
                          __builtin_amdgcn_sched_barrier(0); } while (0)
#define WAIT_VM(n) do { asm volatile("s_waitcnt vmcnt(" #n ")" ::: "memory"); \
                        __builtin_amdgcn_sched_barrier(0); } while (0)

// GEMM1 fused: C = A[M,K] * Bt[N,K]^T with similarity epilogue.
// Swapped-operand MFMA: m-row = lane&15 (+mi*16+wr*128),
//                       n-col = (lane>>4)*4+reg (+ni*16+wc*64).
__global__ __launch_bounds__(512, 2) void gemm8_sim(const u16* __restrict__ A,
                                                    const u16* __restrict__ Bt,
                                                    int Mdim, int Ndim, int Kdim,
                                                    float* __restrict__ out, int ldo,
                                                    const float* __restrict__ a_sq,
                                                    const float* __restrict__ b_sq,
                                                    float* __restrict__ rowsum,
                                                    u16* __restrict__ wb) {
  constexpr int BM = 256, BN = 256, BK = 64;
  __shared__ __align__(16) u16 smA[2][2][8192];   // [buf][half][128*64] 64 KiB
  __shared__ __align__(16) u16 smB[2][2][8192];   // 64 KiB

  const int nTilesN = Ndim / BN;
  const int nwg = (Mdim / BM) * nTilesN;          // 512 for GEMM1 (mult of 8)
  const int cpx = nwg >> 3;
  const int wg = blockIdx.x;
  const int swzb = (wg & 7) * cpx + (wg >> 3);    // XCD swizzle
  const int m0 = (swzb / nTilesN) * BM;
  const int n0 = (swzb % nTilesN) * BN;

  const int t = threadIdx.x;
  const int l = t & 63;
  const int wid = t >> 6;        // 0..7
  const int wr = wid >> 2;       // 0..1  (M)
  const int wc = wid & 3;        // 0..3  (N)
  const int lrow = l & 15;
  const int kb16 = (l >> 4) << 4;          // byte offset 0/16/32/48
  const int lr8 = l >> 3;
  const int cswz = ((l & 7) ^ lr8) << 3;   // pre-swizzled source col (elems)
  const int st_r0 = wid * 16 + lr8;        // stage rows for issue 0/1
  const int st_r1 = wid * 16 + 8 + lr8;
  const int bhalf = wc >> 1;
  const int brow0 = (wc & 1) * 64;

#define STAGE_A8(bufp, half, kelem) do { \
    async16(A + (size_t)(m0 + (half)*128 + st_r0) * Kdim + (kelem) + cswz, \
            &smA[bufp][half][(wid*2 + 0) * 512]); \
    async16(A + (size_t)(m0 + (half)*128 + st_r1) * Kdim + (kelem) + cswz, \
            &smA[bufp][half][(wid*2 + 1) * 512]); } while (0)
#define STAGE_B8(bufp, half, kelem) do { \
    async16(Bt + (size_t)(n0 + (half)*128 + st_r0) * Kdim + (kelem) + cswz, \
            &smB[bufp][half][(wid*2 + 0) * 512]); \
    async16(Bt + (size_t)(n0 + (half)*128 + st_r1) * Kdim + (kelem) + cswz, \
            &smB[bufp][half][(wid*2 + 1) * 512]); } while (0)

  f32x4 acc[8][4];
#pragma unroll
  for (int i = 0; i < 8; ++i)
#pragma unroll
    for (int j = 0; j < 4; ++j) acc[i][j] = (f32x4){0.f, 0.f, 0.f, 0.f};

  short8 af[4][2], bf[4][2];

  // prologue: A(0), B(0), B(1); wait A(0)+B(0) (allow B(1)'s 4 in flight)
  STAGE_A8(0, 0, 0); STAGE_A8(0, 1, 0);
  STAGE_B8(0, 0, 0); STAGE_B8(0, 1, 0);
  STAGE_B8(1, 0, BK); STAGE_B8(1, 1, BK);
  WAIT_VM(4);
  BAR();

  // per-tile macro.  buf_ = u&1.  A(u+1) -> buf^1 at P1/P2 (region consumed
  // at tile u-1 P3).  B(u+2) -> buf_ at P3/P4 (B fully consumed by P2).
  // vmcnt(4): leaves only B(u+2)'s 4 loads outstanding at tile end.
#define DO_TILE8(u_, buf_, doA_, doB_, VMN_) do { \
    /* P1: a-lo + b-lo reads; stage A-h0(u+1) */ \
    _Pragma("unroll") for (int mi = 0; mi < 4; ++mi) { \
      af[mi][0] = lds_frag(&smA[buf_][wr][0], mi*16 + lrow, kb16); \
      af[mi][1] = lds_frag(&smA[buf_][wr][0], mi*16 + lrow, 64 + kb16); } \
    _Pragma("unroll") for (int ni = 0; ni < 2; ++ni) { \
      bf[ni][0] = lds_frag(&smB[buf_][bhalf][0], brow0 + ni*16 + lrow, kb16); \
      bf[ni][1] = lds_frag(&smB[buf_][bhalf][0], brow0 + ni*16 + lrow, 64 + kb16); } \
    if (doA_) STAGE_A8((buf_) ^ 1, 0, ((u_) + 1) * BK); \
    BAR(); WAIT_LGKM0(); \
    __builtin_amdgcn_s_setprio(1); \
    mfma_q<0, 0>(acc, af, bf); \
    __builtin_amdgcn_s_setprio(0); \
    BAR(); \
    /* P2: b-hi reads; stage A-h1(u+1) */ \
    _Pragma("unroll") for (int ni = 2; ni < 4; ++ni) { \
      bf[ni][0] = lds_frag(&smB[buf_][bhalf][0], brow0 + ni*16 + lrow, kb16); \
      bf[ni][1] = lds_frag(&smB[buf_][bhalf][0], brow0 + ni*16 + lrow, 64 + kb16); } \
    if (doA_) STAGE_A8((buf_) ^ 1, 1, ((u_) + 1) * BK); \
    BAR(); WAIT_LGKM0(); \
    __builtin_amdgcn_s_setprio(1); \
    mfma_q<0, 2>(acc, af, bf); \
    __builtin_amdgcn_s_setprio(0); \
    BAR(); \
    /* P3: a-hi reads; stage B-h0(u+2) */ \
    _Pragma("unroll") for (int mi = 0; mi < 4; ++mi) { \
      af[mi][0] = lds_frag(&smA[buf_][wr][0], (mi+4)*16 + lrow, kb16); \
      af[mi][1] = lds_frag(&smA[buf_][wr][0], (mi+4)*16 + lrow, 64 + kb16); } \
    if (doB_) STAGE_B8(buf_, 0, ((u_) + 2) * BK); \
    BAR(); WAIT_LGKM0(); \
    __builtin_amdgcn_s_setprio(1); \
    mfma_q<4, 0>(acc, af, bf); \
    __builtin_amdgcn_s_setprio(0); \
    BAR(); \
    /* P4: no reads; stage B-h1(u+2) */ \
    if (doB_) STAGE_B8(buf_, 1, ((u_) + 2) * BK); \
    BAR(); \
    __builtin_amdgcn_s_setprio(1); \
    mfma_q<4, 2>(acc, af, bf); \
    __builtin_amdgcn_s_setprio(0); \
    WAIT_VM(VMN_); \
    BAR(); \
  } while (0)

  const int T = Kdim / BK;   // 16
  for (int it = 0; it < T / 2 - 1; ++it) {
    const int u0 = 2 * it;
    DO_TILE8(u0, 0, true, true, 4);
    DO_TILE8(u0 + 1, 1, true, true, 4);
  }
  DO_TILE8(T - 2, 0, true, false, 0);
  DO_TILE8(T - 1, 1, false, false, 0);

  // epilogue: m = lane&15 (+mi*16+wr*128), n = (lane>>4)*4+r (+ni*16+wc*64)
  const int rgrp = l >> 4;
#pragma unroll
  for (int mi = 0; mi < 8; ++mi) {
    int grow = m0 + wr * 128 + mi * 16 + lrow;
    float zq = a_sq[grow];
    float esum = 0.f;
#pragma unroll
    for (int ni = 0; ni < 4; ++ni) {
      int ncol = n0 + wc * 64 + ni * 16 + rgrp * 4;
      f32x4 eqv = *(const f32x4*)(b_sq + ncol);
      f32x4 simv;
      ushort4 wv;
#pragma unroll
      for (int r = 0; r < 4; ++r) {
        float dist2 = fmaxf(zq + eqv[r] - 2.0f * acc[mi][ni][r], 0.0f);
        float sim = __expf(-0.5f * dist2);
        simv[r] = sim;
        float es = __expf(sim);    // softmax numerator (sim in [0,1])
        (&wv.x)[r] = f32_to_bf16(es);
        esum += es;
      }
      *(f32x4*)(out + (size_t)grow * ldo + ncol) = simv;
      *(ushort4*)(wb + (size_t)grow * ldo + ncol) = wv;
    }
    esum += __shfl_xor(esum, 16, 64);
    esum += __shfl_xor(esum, 32, 64);
    if (rgrp == 0) atomicAdd(&rowsum[grow], esum);
  }
#undef DO_TILE8
#undef STAGE_A8
#undef STAGE_B8
}

// ===================== 128x128 dbuf kernel (GEMM2 + fallback) ==============
template <int EPI>
__global__ __launch_bounds__(256) void gemm_bt(const u16* __restrict__ A,
                                               const u16* __restrict__ Bt,
                                               int Mdim, int Ndim, int Kdim,
                                               float* __restrict__ out, int ldo,
                                               const float* __restrict__ a_sq,
                                               const float* __restrict__ b_sq,
                                               float* __restrict__ rowsum,
                                               u16* __restrict__ wb,
                                               const float* __restrict__ scale) {
  constexpr int BM = 128, BN = 128, BK = 64;
  __shared__ __align__(16) u16 smA[2 * BM * BK];
  __shared__ __align__(16) u16 smB[2 * BN * BK];

  const int nTilesN = Ndim / BN;
  const int nwg = (Mdim / BM) * nTilesN;
  const int cpx = nwg >> 3;
  const int wg = blockIdx.x;
  const int swz = (wg & 7) * cpx + (wg >> 3);
  const int m0 = (swz / nTilesN) * BM;
  const int n0 = (swz % nTilesN) * BN;

  const int t = threadIdx.x;
  const int l = t & 63;
  const int w = t >> 6;
  const int wr = w >> 1, wc = w & 1;
  const int lr8 = l >> 3;
  const int cswz = (((l & 7) ^ lr8) << 3);

  f32x4 acc[4][4];
#pragma unroll
  for (int i = 0; i < 4; ++i)
#pragma unroll
    for (int j = 0; j < 4; ++j) acc[i][j] = (f32x4){0.f, 0.f, 0.f, 0.f};

  const int nIter = Kdim / BK;
#pragma unroll
  for (int i = 0; i < 4; ++i) {
    int s = i * 4 + w;
    int row = s * 8 + lr8;
    async16(A + (size_t)(m0 + row) * Kdim + cswz, smA + s * 512);
    async16(Bt + (size_t)(n0 + row) * Kdim + cswz, smB + s * 512);
  }
  __syncthreads();

  int cur = 0;
  for (int it = 0; it < nIter; ++it) {
    if (it + 1 < nIter) {
      const int k0 = (it + 1) * BK;
      const int nb = (cur ^ 1) * 8192;
#pragma unroll
      for (int i = 0; i < 4; ++i) {
        int s = i * 4 + w;
        int row = s * 8 + lr8;
        async16(A + (size_t)(m0 + row) * Kdim + k0 + cswz, smA + nb + s * 512);
        async16(Bt + (size_t)(n0 + row) * Kdim + k0 + cswz, smB + nb + s * 512);
      }
    }
    const int cbase = cur * 8192;
#pragma unroll
    for (int ks = 0; ks < 2; ++ks) {
      short8 af[4], bf[4];
      const int lrow = l & 15;
      const int kb = ks * 64 + ((l >> 4) << 4);
#pragma unroll
      for (int mi = 0; mi < 4; ++mi) {
        int row = wr * 64 + mi * 16 + lrow;
        int addr = row * 128 + (kb ^ ((row & 7) << 4));
        af[mi] = *(const short8*)(smA + cbase + (addr >> 1));
      }
#pragma unroll
      for (int ni = 0; ni < 4; ++ni) {
        int row = wc * 64 + ni * 16 + lrow;
        int addr = row * 128 + (kb ^ ((row & 7) << 4));
        bf[ni] = *(const short8*)(smB + cbase + (addr >> 1));
      }
#pragma unroll
      for (int mi = 0; mi < 4; ++mi)
#pragma unroll
        for (int ni = 0; ni < 4; ++ni)
          acc[mi][ni] = __builtin_amdgcn_mfma_f32_16x16x32_bf16(
              bf[ni], af[mi], acc[mi][ni], 0, 0, 0);
    }
    __syncthreads();
    cur ^= 1;
  }

  const int lcol = l & 15;
  const int rgrp = l >> 4;
  if (EPI == 1) {
#pragma unroll
    for (int mi = 0; mi < 4; ++mi) {
      int grow = m0 + wr * 64 + mi * 16 + lcol;
      float zq = a_sq[grow];
      float esum = 0.f;
#pragma unroll
      for (int ni = 0; ni < 4; ++ni) {
        int ncol = n0 + wc * 64 + ni * 16 + rgrp * 4;
        f32x4 eqv = *(const f32x4*)(b_sq + ncol);
        f32x4 simv;
        ushort4 wv;
#pragma unroll
        for (int r = 0; r < 4; ++r) {
          float dist2 = fmaxf(zq + eqv[r] - 2.0f * acc[mi][ni][r], 0.0f);
          float sim = __expf(-0.5f * dist2);
          simv[r] = sim;
          float es = __expf(sim);
          (&wv.x)[r] = f32_to_bf16(es);
          esum += es;
        }
        *(f32x4*)(out + (size_t)grow * ldo + ncol) = simv;
        if (wb) *(ushort4*)(wb + (size_t)grow * ldo + ncol) = wv;
      }
      esum += __shfl_xor(esum, 16, 64);
      esum += __shfl_xor(esum, 32, 64);
      if (rgrp == 0) atomicAdd(&rowsum[grow], esum);
    }
  } else {
#pragma unroll
    for (int mi = 0; mi < 4; ++mi) {
      int grow = m0 + wr * 64 + mi * 16 + lcol;
      float s = scale ? (1.0f / scale[grow]) : 1.0f;
#pragma unroll
      for (int ni = 0; ni < 4; ++ni) {
        int ncol = n0 + wc * 64 + ni * 16 + rgrp * 4;
        f32x4 v = acc[mi][ni] * s;
        *(f32x4*)(out + (size_t)grow * ldo + ncol) = v;
      }
    }
  }
}

// ---- weights (fallback path only) -----------------------------------------
__global__ __launch_bounds__(256) void weights_kernel(const float* __restrict__ sim,
                                                      const float* __restrict__ rowsum,
                                                      u16* __restrict__ wb) {
  size_t i = ((size_t)blockIdx.x * 256 + threadIdx.x) * 8;
  int row = (int)(i >> 12);
  float inv = 1.0f / rowsum[row];
  float4 a = *(const float4*)(sim + i);
  float4 b = *(const float4*)(sim + i + 4);
  u32 w0 = (u32)f32_to_bf16(__expf(a.x) * inv) | ((u32)f32_to_bf16(__expf(a.y) * inv) << 16);
  u32 w1 = (u32)f32_to_bf16(__expf(a.z) * inv) | ((u32)f32_to_bf16(__expf(a.w) * inv) << 16);
  u32 w2 = (u32)f32_to_bf16(__expf(b.x) * inv) | ((u32)f32_to_bf16(__expf(b.y) * inv) << 16);
  u32 w3 = (u32)f32_to_bf16(__expf(b.z) * inv) | ((u32)f32_to_bf16(__expf(b.w) * inv) << 16);
  uint4 o; o.x = w0; o.y = w1; o.z = w2; o.w = w3;
  *(uint4*)(wb + i) = o;
}

extern "C" void kernel_launch(void* const* d_in, const int* in_sizes, int n_in,
                              void* d_out, int out_size, void* d_ws, size_t ws_size,
                              hipStream_t stream) {
  const float* z = (const float*)d_in[0];
  const float* e = (const float*)d_in[1];
  float* out = (float*)d_out;
  float* sim = out;                                   // [8192,4096]
  float* wout = out + (size_t)M_TOK * N_EXP;          // [8192,1024]

  char* ws = (char*)d_ws;
  const size_t MB = (size_t)1 << 20;
  const bool fused = ws_size >= 96 * MB + 80 * 1024;

  if (fused) {
    u16* zb  = (u16*)ws;                              // 16 MiB
    u16* eb  = (u16*)(ws + 16 * MB);                  // 8 MiB
    u16* ebT = (u16*)(ws + 24 * MB);                  // 8 MiB
    u16* Wb  = (u16*)(ws + 32 * MB);                  // 64 MiB
    float* z_sq   = (float*)(ws + 96 * MB);
    float* e_sq   = (float*)(ws + 96 * MB + 32768);
    float* rowsum = (float*)(ws + 96 * MB + 49152);

    prep_convert2<<<M_TOK + N_EXP, 256, 0, stream>>>(z, e, zb, eb, z_sq, e_sq);
    transpose_bf16<<<dim3(N_EXP / 64, D_DIM / 64), 256, 0, stream>>>(eb, ebT);
    (void)hipMemsetAsync(rowsum, 0, M_TOK * sizeof(float), stream);

    // GEMM1 (8-phase 256x256): sim -> out, bf16(exp(sim)) -> Wb, rowsum
    gemm8_sim<<<(M_TOK / 256) * (N_EXP / 256), 512, 0, stream>>>(
        zb, eb, M_TOK, N_EXP, D_DIM, sim, N_EXP, z_sq, e_sq, rowsum, Wb);

    // GEMM2: wout = (expsim @ E) / rowsum[row]
    gemm_bt<0><<<(M_TOK / 128) * (D_DIM / 128), 256, 0, stream>>>(
        Wb, ebT, M_TOK, D_DIM, N_EXP, wout, D_DIM, nullptr, nullptr, nullptr,
        nullptr, rowsum);
  } else {
    u16* Wb  = (u16*)ws;
    u16* zb  = (u16*)ws;
    u16* eb  = (u16*)(ws + 64 * MB);
    u16* ebT = (u16*)(ws + 72 * MB);
    float* z_sq   = (float*)(ws + 80 * MB);
    float* e_sq   = (float*)(ws + 80 * MB + 32768);
    float* rowsum = (float*)(ws + 80 * MB + 49152);

    prep_convert2<<<M_TOK + N_EXP, 256, 0, stream>>>(z, e, zb, eb, z_sq, e_sq);
    transpose_bf16<<<dim3(N_EXP / 64, D_DIM / 64), 256, 0, stream>>>(eb, ebT);
    (void)hipMemsetAsync(rowsum, 0, M_TOK * sizeof(float), stream);

    gemm_bt<1><<<(M_TOK / 128) * (N_EXP / 128), 256, 0, stream>>>(
        zb, eb, M_TOK, N_EXP, D_DIM, sim, N_EXP, z_sq, e_sq, rowsum, nullptr, nullptr);

    weights_kernel<<<(M_TOK * (size_t)N_EXP) / (8 * 256), 256, 0, stream>>>(sim, rowsum, Wb);

    gemm_bt<0><<<(M_TOK / 128) * (D_DIM / 128), 256, 0, stream>>>(
        Wb, ebT, M_TOK, D_DIM, N_EXP, wout, D_DIM, nullptr, nullptr, nullptr,
        nullptr, nullptr);
  }
}

// Round 7
// 189.832 us; speedup vs baseline: 1.2448x; 1.0072x over previous
//
#include <hip/hip_runtime.h>
#include <stdint.h>

// GaussianKernelSimilarity: z[8192,1024] f32, expert_keys[4096,1024] f32
// out0 = exp(-max(|z|^2+|e|^2-2 z.e, 0)/2)  [8192,4096]
// out1 = softmax(out0, axis=-1) @ expert_keys [8192,1024]
//
// Round 7: K-loop = round-5 dbuf 128x128 (best measured). NEW: full-line
// epilogue. Each wave transposes its 16x64 output tile through wave-private
// (dead) staging LDS so each global store writes full cache lines:
//   sim: 4 rows x 256 B per f32x4 instruction, NON-TEMPORAL (never re-read,
//        bypasses L3 -> stops evicting A/B panels; round-5 FETCH was 195 MB
//        = 8x input because the 192 MB write stream cycled L3)
//   Wb:  4 rows x 128 B per instruction, cached (GEMM2 re-reads it)
// Round-3's nt regression (+36 MB WRITE) was partial-line RMW on 64-B
// segments; full lines avoid it.

#define M_TOK 8192
#define N_EXP 4096
#define D_DIM 1024

typedef __attribute__((ext_vector_type(4))) float f32x4;
typedef __attribute__((ext_vector_type(8))) short short8;
typedef __attribute__((ext_vector_type(4))) unsigned short u16x4;
typedef unsigned short u16;
typedef unsigned int u32;

__device__ __forceinline__ u16 f32_to_bf16(float f) {
  u32 u = __builtin_bit_cast(u32, f);
  u += 0x7fff + ((u >> 16) & 1);   // round-to-nearest-even
  return (u16)(u >> 16);
}

__device__ __forceinline__ void async16(const void* g, void* l) {
  __builtin_amdgcn_global_load_lds((__attribute__((address_space(1))) void*)(g),
                                   (__attribute__((address_space(3))) void*)(l),
                                   16, 0, 0);
}

// ---- prep: f32 -> bf16 convert + row |.|^2 for BOTH z and e (one launch) --
__global__ __launch_bounds__(256) void prep_convert2(const float* __restrict__ zsrc,
                                                     const float* __restrict__ esrc,
                                                     u16* __restrict__ zdst,
                                                     u16* __restrict__ edst,
                                                     float* __restrict__ zsq,
                                                     float* __restrict__ esq) {
  int row = blockIdx.x;
  const float* src;
  u16* dst;
  float* sq;
  if (row < M_TOK) {
    src = zsrc + (size_t)row * D_DIM;
    dst = zdst + (size_t)row * D_DIM;
    sq = zsq + row;
  } else {
    int r = row - M_TOK;
    src = esrc + (size_t)r * D_DIM;
    dst = edst + (size_t)r * D_DIM;
    sq = esq + r;
  }
  int t = threadIdx.x;                       // 256 threads, 4 elems each
  const float4 v = ((const float4*)src)[t];
  ushort4 h;
  h.x = f32_to_bf16(v.x); h.y = f32_to_bf16(v.y);
  h.z = f32_to_bf16(v.z); h.w = f32_to_bf16(v.w);
  ((ushort4*)dst)[t] = h;
  float p = v.x * v.x + v.y * v.y + v.z * v.z + v.w * v.w;
#pragma unroll
  for (int off = 1; off < 64; off <<= 1) p += __shfl_xor(p, off, 64);
  __shared__ float partial[4];
  if ((t & 63) == 0) partial[t >> 6] = p;
  __syncthreads();
  if (t == 0) *sq = partial[0] + partial[1] + partial[2] + partial[3];
}

// ---- bf16 transpose: eb[4096][1024] -> ebT[1024][4096] --------------------
__global__ __launch_bounds__(256) void transpose_bf16(const u16* __restrict__ src,
                                                      u16* __restrict__ dst) {
  __shared__ u16 tile[64][65];
  int e0 = blockIdx.x * 64;
  int d0 = blockIdx.y * 64;
  int t = threadIdx.x;
  int lr = t >> 4;
  int lc = (t & 15) * 4;
#pragma unroll
  for (int r8 = 0; r8 < 4; ++r8) {
    int row = lr + r8 * 16;
    ushort4 v = *(const ushort4*)(src + (size_t)(e0 + row) * D_DIM + d0 + lc);
    tile[row][lc + 0] = v.x; tile[row][lc + 1] = v.y;
    tile[row][lc + 2] = v.z; tile[row][lc + 3] = v.w;
  }
  __syncthreads();
#pragma unroll
  for (int r8 = 0; r8 < 4; ++r8) {
    int dl = lr + r8 * 16;
    ushort4 v;
    v.x = tile[lc + 0][dl]; v.y = tile[lc + 1][dl];
    v.z = tile[lc + 2][dl]; v.w = tile[lc + 3][dl];
    *(ushort4*)(dst + (size_t)(d0 + dl) * N_EXP + e0 + lc) = v;
  }
}

// ---- gemm_bt: C[M,N] = A[M,K] * Bt[N,K]^T, bf16 MFMA 16x16x32 -------------
// 128x128 tile, BK=64, 4 waves (2x2), double-buffered LDS. Per K-step:
// issue next tile's global_load_lds, ds_read+MFMA current, one barrier.
// SWAPPED operands: mfma(bf, af, acc):
//   m-row = lane&15 (+mi*16+wr*64), n-col = (lane>>4)*4+reg (+ni*16+wc*64)
// EPI=1 epilogue: per (wave,mi) 16x64 sim tile staged in wave-private LDS
// (reusing dead smA) -> transposed readback -> full-line stores:
//   sim non-temporal f32x4 (4 rows x 256B/instr), Wb cached (4 rows x 128B).
// EPI=0: store acc * (1/scale[row]).
template <int EPI>
__global__ __launch_bounds__(256) void gemm_bt(const u16* __restrict__ A,
                                               const u16* __restrict__ Bt,
                                               int Mdim, int Ndim, int Kdim,
                                               float* __restrict__ out, int ldo,
                                               const float* __restrict__ a_sq,
                                               const float* __restrict__ b_sq,
                                               float* __restrict__ rowsum,
                                               u16* __restrict__ wb,
                                               const float* __restrict__ scale) {
  constexpr int BM = 128, BN = 128, BK = 64;
  __shared__ __align__(16) u16 smA[2 * BM * BK];   // 32 KiB
  __shared__ __align__(16) u16 smB[2 * BN * BK];   // 32 KiB

  const int nTilesN = Ndim / BN;
  const int nwg = (Mdim / BM) * nTilesN;
  const int cpx = nwg >> 3;
  const int wg = blockIdx.x;
  const int swz = (wg & 7) * cpx + (wg >> 3);      // XCD-aware swizzle
  const int m0 = (swz / nTilesN) * BM;
  const int n0 = (swz % nTilesN) * BN;

  const int t = threadIdx.x;
  const int l = t & 63;
  const int w = t >> 6;
  const int wr = w >> 1, wc = w & 1;
  const int lr8 = l >> 3;
  const int cswz = (((l & 7) ^ lr8) << 3);

  f32x4 acc[4][4];
#pragma unroll
  for (int i = 0; i < 4; ++i)
#pragma unroll
    for (int j = 0; j < 4; ++j) acc[i][j] = (f32x4){0.f, 0.f, 0.f, 0.f};

  const int nIter = Kdim / BK;
#pragma unroll
  for (int i = 0; i < 4; ++i) {
    int s = i * 4 + w;
    int row = s * 8 + lr8;
    async16(A + (size_t)(m0 + row) * Kdim + cswz, smA + s * 512);
    async16(Bt + (size_t)(n0 + row) * Kdim + cswz, smB + s * 512);
  }
  __syncthreads();

  int cur = 0;
  for (int it = 0; it < nIter; ++it) {
    if (it + 1 < nIter) {
      const int k0 = (it + 1) * BK;
      const int nb = (cur ^ 1) * 8192;
#pragma unroll
      for (int i = 0; i < 4; ++i) {
        int s = i * 4 + w;
        int row = s * 8 + lr8;
        async16(A + (size_t)(m0 + row) * Kdim + k0 + cswz, smA + nb + s * 512);
        async16(Bt + (size_t)(n0 + row) * Kdim + k0 + cswz, smB + nb + s * 512);
      }
    }
    const int cbase = cur * 8192;
#pragma unroll
    for (int ks = 0; ks < 2; ++ks) {
      short8 af[4], bf[4];
      const int lrow = l & 15;
      const int kb = ks * 64 + ((l >> 4) << 4);
#pragma unroll
      for (int mi = 0; mi < 4; ++mi) {
        int row = wr * 64 + mi * 16 + lrow;
        int addr = row * 128 + (kb ^ ((row & 7) << 4));
        af[mi] = *(const short8*)(smA + cbase + (addr >> 1));
      }
#pragma unroll
      for (int ni = 0; ni < 4; ++ni) {
        int row = wc * 64 + ni * 16 + lrow;
        int addr = row * 128 + (kb ^ ((row & 7) << 4));
        bf[ni] = *(const short8*)(smB + cbase + (addr >> 1));
      }
#pragma unroll
      for (int mi = 0; mi < 4; ++mi)
#pragma unroll
        for (int ni = 0; ni < 4; ++ni)
          acc[mi][ni] = __builtin_amdgcn_mfma_f32_16x16x32_bf16(
              bf[ni], af[mi], acc[mi][ni], 0, 0, 0);
    }
    __syncthreads();   // drains vmcnt/lgkm; next buffer ready, cur reusable
    cur ^= 1;
  }
  // NOTE: final __syncthreads above means all waves are done reading smA/smB
  // -> safe to reuse smA as epilogue scratch (wave-private regions).

  const int lcol = l & 15;
  const int rgrp = l >> 4;
  if (EPI == 1) {
    // wave-private transpose scratch: 16 rows x 68 floats (pad +4) = 4352 B
    float* ldsT = ((float*)smA) + w * (16 * 68);
#pragma unroll
    for (int mi = 0; mi < 4; ++mi) {
      int grow = m0 + wr * 64 + mi * 16 + lcol;
      float zq = a_sq[grow];
      float esum = 0.f;
#pragma unroll
      for (int ni = 0; ni < 4; ++ni) {
        int ncol = n0 + wc * 64 + ni * 16 + rgrp * 4;
        f32x4 eqv = *(const f32x4*)(b_sq + ncol);
        f32x4 simv;
#pragma unroll
        for (int r = 0; r < 4; ++r) {
          float dist2 = fmaxf(zq + eqv[r] - 2.0f * acc[mi][ni][r], 0.0f);
          float sim = __expf(-0.5f * dist2);
          simv[r] = sim;
          esum += __expf(sim);   // softmax numerator (sim in [0,1], no max-sub)
        }
        // stage: lds[lcol][ni*16 + rgrp*4 .. +3]
        *(f32x4*)(ldsT + lcol * 68 + ni * 16 + rgrp * 4) = simv;
      }
      // lanes l, l+16, l+32, l+48 share grow -> butterfly over bits 4,5
      esum += __shfl_xor(esum, 16, 64);
      esum += __shfl_xor(esum, 32, 64);
      if (rgrp == 0) atomicAdd(&rowsum[grow], esum);

      // transposed readback: per s, lanes cover 4 rows x 64 cols
      // (full-line stores: sim 4x256B nt, Wb 4x128B cached)
#pragma unroll
      for (int s = 0; s < 4; ++s) {
        int rrow = (l >> 4) + 4 * s;               // 0..15
        f32x4 sv = *(const f32x4*)(ldsT + rrow * 68 + (l & 15) * 4);
        size_t gbase = (size_t)(m0 + wr * 64 + mi * 16 + rrow) * ldo +
                       (n0 + wc * 64 + (l & 15) * 4);
        __builtin_nontemporal_store(sv, (f32x4*)(out + gbase));
        if (wb) {
          u16x4 wv;
          wv.x = f32_to_bf16(__expf(sv[0]));
          wv.y = f32_to_bf16(__expf(sv[1]));
          wv.z = f32_to_bf16(__expf(sv[2]));
          wv.w = f32_to_bf16(__expf(sv[3]));
          *(u16x4*)(wb + gbase) = wv;
        }
      }
    }
  } else {
#pragma unroll
    for (int mi = 0; mi < 4; ++mi) {
      int grow = m0 + wr * 64 + mi * 16 + lcol;
      float s = scale ? (1.0f / scale[grow]) : 1.0f;
#pragma unroll
      for (int ni = 0; ni < 4; ++ni) {
        int ncol = n0 + wc * 64 + ni * 16 + rgrp * 4;
        f32x4 v = acc[mi][ni] * s;
        *(f32x4*)(out + (size_t)grow * ldo + ncol) = v;
      }
    }
  }
}

// ---- weights (fallback path only) -----------------------------------------
__global__ __launch_bounds__(256) void weights_kernel(const float* __restrict__ sim,
                                                      const float* __restrict__ rowsum,
                                                      u16* __restrict__ wb) {
  size_t i = ((size_t)blockIdx.x * 256 + threadIdx.x) * 8;
  int row = (int)(i >> 12);
  float inv = 1.0f / rowsum[row];
  float4 a = *(const float4*)(sim + i);
  float4 b = *(const float4*)(sim + i + 4);
  u32 w0 = (u32)f32_to_bf16(__expf(a.x) * inv) | ((u32)f32_to_bf16(__expf(a.y) * inv) << 16);
  u32 w1 = (u32)f32_to_bf16(__expf(a.z) * inv) | ((u32)f32_to_bf16(__expf(a.w) * inv) << 16);
  u32 w2 = (u32)f32_to_bf16(__expf(b.x) * inv) | ((u32)f32_to_bf16(__expf(b.y) * inv) << 16);
  u32 w3 = (u32)f32_to_bf16(__expf(b.z) * inv) | ((u32)f32_to_bf16(__expf(b.w) * inv) << 16);
  uint4 o; o.x = w0; o.y = w1; o.z = w2; o.w = w3;
  *(uint4*)(wb + i) = o;
}

extern "C" void kernel_launch(void* const* d_in, const int* in_sizes, int n_in,
                              void* d_out, int out_size, void* d_ws, size_t ws_size,
                              hipStream_t stream) {
  const float* z = (const float*)d_in[0];
  const float* e = (const float*)d_in[1];
  float* out = (float*)d_out;
  float* sim = out;                                   // [8192,4096]
  float* wout = out + (size_t)M_TOK * N_EXP;          // [8192,1024]

  char* ws = (char*)d_ws;
  const size_t MB = (size_t)1 << 20;
  const bool fused = ws_size >= 96 * MB + 80 * 1024;

  if (fused) {
    u16* zb  = (u16*)ws;                              // 16 MiB
    u16* eb  = (u16*)(ws + 16 * MB);                  // 8 MiB
    u16* ebT = (u16*)(ws + 24 * MB);                  // 8 MiB
    u16* Wb  = (u16*)(ws + 32 * MB);                  // 64 MiB
    float* z_sq   = (float*)(ws + 96 * MB);
    float* e_sq   = (float*)(ws + 96 * MB + 32768);
    float* rowsum = (float*)(ws + 96 * MB + 49152);

    prep_convert2<<<M_TOK + N_EXP, 256, 0, stream>>>(z, e, zb, eb, z_sq, e_sq);
    transpose_bf16<<<dim3(N_EXP / 64, D_DIM / 64), 256, 0, stream>>>(eb, ebT);
    (void)hipMemsetAsync(rowsum, 0, M_TOK * sizeof(float), stream);

    // GEMM1: sim -> out (nt full-line), bf16(exp(sim)) -> Wb, rowsum
    gemm_bt<1><<<(M_TOK / 128) * (N_EXP / 128), 256, 0, stream>>>(
        zb, eb, M_TOK, N_EXP, D_DIM, sim, N_EXP, z_sq, e_sq, rowsum, Wb, nullptr);

    // GEMM2: wout = (expsim @ E) / rowsum[row]
    gemm_bt<0><<<(M_TOK / 128) * (D_DIM / 128), 256, 0, stream>>>(
        Wb, ebT, M_TOK, D_DIM, N_EXP, wout, D_DIM, nullptr, nullptr, nullptr,
        nullptr, rowsum);
  } else {
    u16* Wb  = (u16*)ws;
    u16* zb  = (u16*)ws;
    u16* eb  = (u16*)(ws + 64 * MB);
    u16* ebT = (u16*)(ws + 72 * MB);
    float* z_sq   = (float*)(ws + 80 * MB);
    float* e_sq   = (float*)(ws + 80 * MB + 32768);
    float* rowsum = (float*)(ws + 80 * MB + 49152);

    prep_convert2<<<M_TOK + N_EXP, 256, 0, stream>>>(z, e, zb, eb, z_sq, e_sq);
    transpose_bf16<<<dim3(N_EXP / 64, D_DIM / 64), 256, 0, stream>>>(eb, ebT);
    (void)hipMemsetAsync(rowsum, 0, M_TOK * sizeof(float), stream);

    gemm_bt<1><<<(M_TOK / 128) * (N_EXP / 128), 256, 0, stream>>>(
        zb, eb, M_TOK, N_EXP, D_DIM, sim, N_EXP, z_sq, e_sq, rowsum, nullptr, nullptr);

    weights_kernel<<<(M_TOK * (size_t)N_EXP) / (8 * 256), 256, 0, stream>>>(sim, rowsum, Wb);

    gemm_bt<0><<<(M_TOK / 128) * (D_DIM / 128), 256, 0, stream>>>(
        Wb, ebT, M_TOK, D_DIM, N_EXP, wout, D_DIM, nullptr, nullptr, nullptr,
        nullptr, nullptr);
  }
}